// Round 6
// baseline (1109.215 us; speedup 1.0000x reference)
//
#include <hip/hip_runtime.h>

using fp16 = _Float16;
typedef fp16 f16x4 __attribute__((ext_vector_type(4)));
typedef fp16 f16x8 __attribute__((ext_vector_type(8)));
typedef float f32x4 __attribute__((ext_vector_type(4)));

#define DEVI __device__ __forceinline__

constexpr int LL = 50;
constexpr int BB = 4096;
constexpr int ALPHA = 128;
constexpr int CTX = 20;
constexpr int ATT = 100;
constexpr int EPB = 7;                    // elems per decoder block
constexpr int NBLK = (BB + EPB - 1)/EPB;  // 586

// ---- fragment image element offsets (fp16 elems) ----
constexpr int FQ_OFF  = 0;       // Wq_eff  [K=160][N=112]  NT=7 KT=5
constexpr int FF_OFF  = 17920;   // Wff_eff [K=224][N=128]  NT=8 KT=7
constexpr int FR_OFF  = 46592;   // Wre     [K=128][N=32]   NT=2 KT=4
constexpr int FB_OFF  = 50688;   // Wbc     [K=32][N=32]    NT=2 KT=1
constexpr int FTQ_OFF = 51712;   // Wq tag rows [64][112]   NT=7 KT=2
constexpr int FTF_OFF = 58880;   // Wff tag rows[64][128]   NT=8 KT=2
constexpr int FRAG_TOT= 67072;

// ---- workspace byte offsets ----
constexpr size_t WS_FRAG = 0;
constexpr size_t WS_PQ   = 134144;                     // f32 [50][112]
constexpr size_t WS_PK   = 156544;                     // f32 [50][112]
constexpr size_t WS_TBL  = 178944;                     // f16: ce|em|wk
constexpr int    TBL_CE  = 0;
constexpr int    TBL_EM  = 2560;
constexpr int    TBL_WK  = 7680;
constexpr int    TBL_N   = 15744;
constexpr size_t WS_K    = 210432;                     // f16 [4096][50][104]
constexpr size_t WS_V    = WS_K + (size_t)BB*5200*2;   // f16 [4096][60][52]

// ---- decoder LDS byte offsets (dynamic shared) ----
constexpr int OFF_V  = 0;         // f16 [7][60][52] = 43680
constexpr int OFF_XQ = 43680;     // f16 [16][160]   = 5120
constexpr int OFF_XF = 48800;     // f16 [16][224]   = 7168
constexpr int OFF_RP = 55968;     // f16 [16][40]    = 1280
constexpr int OFF_QB = 57248;     // f16 [8][104]    = 1664   (tagsl overlay in prologue)
constexpr int OFF_SC = 58912;     // f16 [8][132]    = 2112
constexpr int OFF_AT = 61024;     // f16 [8][52]     = 832
constexpr int OFF_TQ = 61856;     // f16 [8][104]    = 1664
constexpr int OFF_TF = 63520;     // f16 [8][128]    = 2048
constexpr int OFF_CX = 65568;     // f16 [8][20]     = 320
constexpr int OFF_BB = 65888;     // f32 [40]        = 160  (bre|bbc)
constexpr int SM_TOT = 66048;     // x2 = 132096 <= 163840 -> 2 blocks/CU

constexpr int XQS = 160, XFS = 224, QBS = 104, SCS = 132, TQS = 104;

DEVI float rcpf(float x) { return __builtin_amdgcn_rcpf(x); }
DEVI float sigm(float x) { return rcpf(1.0f + __expf(-x)); }

DEVI f32x4 mfma16(f16x8 a, f16x8 b, f32x4 c) {
  return __builtin_amdgcn_mfma_f32_16x16x32_f16(a, b, c, 0, 0, 0);
}
DEVI float dot8f(f16x8 a, f16x8 b, float acc) {
  acc = __builtin_amdgcn_fdot2(__builtin_shufflevector(a,a,0,1), __builtin_shufflevector(b,b,0,1), acc, false);
  acc = __builtin_amdgcn_fdot2(__builtin_shufflevector(a,a,2,3), __builtin_shufflevector(b,b,2,3), acc, false);
  acc = __builtin_amdgcn_fdot2(__builtin_shufflevector(a,a,4,5), __builtin_shufflevector(b,b,4,5), acc, false);
  acc = __builtin_amdgcn_fdot2(__builtin_shufflevector(a,a,6,7), __builtin_shufflevector(b,b,6,7), acc, false);
  return acc;
}
DEVI float dot4f(f16x4 a, f16x4 b, float acc) {
  acc = __builtin_amdgcn_fdot2(__builtin_shufflevector(a,a,0,1), __builtin_shufflevector(b,b,0,1), acc, false);
  acc = __builtin_amdgcn_fdot2(__builtin_shufflevector(a,a,2,3), __builtin_shufflevector(b,b,2,3), acc, false);
  return acc;
}

// DPP all-VALU wave64 reductions. REQUIRES v >= 0 (bound_ctrl 0-fill safe).
#define DPP_STEP(OP, CTRL)                                                        \
  { int t_ = __builtin_amdgcn_update_dpp(0, __builtin_bit_cast(int, v), CTRL, 0xF, 0xF, true); \
    v = OP(v, __builtin_bit_cast(float, t_)); }
DEVI float addf(float a, float b) { return a + b; }
DEVI float redmax64(float v) {
  DPP_STEP(fmaxf, 0x111) DPP_STEP(fmaxf, 0x112) DPP_STEP(fmaxf, 0x114)
  DPP_STEP(fmaxf, 0x118) DPP_STEP(fmaxf, 0x142) DPP_STEP(fmaxf, 0x143)
  return __builtin_bit_cast(float, __builtin_amdgcn_readlane(__builtin_bit_cast(int, v), 63));
}
DEVI float redsum64(float v) {
  DPP_STEP(addf, 0x111) DPP_STEP(addf, 0x112) DPP_STEP(addf, 0x114)
  DPP_STEP(addf, 0x118) DPP_STEP(addf, 0x142) DPP_STEP(addf, 0x143)
  return __builtin_bit_cast(float, __builtin_amdgcn_readlane(__builtin_bit_cast(int, v), 63));
}

// LDS-only barrier: all cross-wave deps in this kernel are through LDS; global
// stores (out) are wave-private, so no vmcnt drain needed.
DEVI void lbar() { asm volatile("s_waitcnt lgkmcnt(0)\ns_barrier" ::: "memory"); }

// ================= setup: tables + fragment-packed weights =================
__global__ void dt_setup(const float* __restrict__ embT, const float* __restrict__ Wce,
                         const float* __restrict__ bce,
                         const float* __restrict__ Wq, const float* __restrict__ bq,
                         const float* __restrict__ Wk, const float* __restrict__ bk,
                         const float* __restrict__ Wff, const float* __restrict__ Wre,
                         const float* __restrict__ Wbc, char* __restrict__ ws) {
  __shared__ float ap[LL*60];
  const int tid = threadIdx.x, bid = blockIdx.x;
  if (bid <= 1) {
    for (int i = tid; i < LL*30; i += 256) {
      int p = i / 30, k = i % 30;
      float freq = powf(10000.f, 2.0f*(float)k/60.0f);
      float ang = (float)p / freq;
      ap[p*60 + k]      = sinf(ang);
      ap[p*60 + 30 + k] = cosf(ang);
    }
    __syncthreads();
    const float* W = (bid == 0) ? Wq : Wk;
    const float* bi = (bid == 0) ? bq : bk;
    float* dst = (float*)(ws + (bid == 0 ? WS_PQ : WS_PK));
    for (int i = tid; i < LL*112; i += 256) {
      int r = i / 112, j = i % 112;
      float a = 0.f;
      if (j < ATT) {
        a = bi[j];
        for (int f = 0; f < 60; ++f) a += ap[r*60 + f]*W[f*ATT + j];
      }
      dst[i] = a;
    }
  } else if (bid == 2) {
    fp16* tbl = (fp16*)(ws + WS_TBL);
    for (int i = tid; i < ALPHA*CTX; i += 256) {
      int r = i / CTX, o = i % CTX;
      float a = bce[o];
      for (int e = 0; e < 40; ++e) a += embT[r*40 + e]*Wce[e*CTX + o];
      tbl[TBL_CE + i] = (fp16)a;
    }
    for (int i = tid; i < ALPHA*40; i += 256) tbl[TBL_EM + i] = (fp16)embT[i];
  } else if (bid == 3) {
    fp16* tbl = (fp16*)(ws + WS_TBL);
    for (int i = tid; i < 112*72; i += 256) {
      int a = i / 72, c = i % 72;
      float v = 0.f;
      if (a < ATT) {
        if (c < 20)      v = Wk[(60 + c)*ATT + a];
        else if (c < 60) v = Wk[(80 + (c-20))*ATT + a];
      }
      tbl[TBL_WK + i] = (fp16)v;
    }
  } else {
    fp16* pw = (fp16*)(ws + WS_FRAG);
    for (int gi = (bid-4)*256 + tid; gi < FRAG_TOT; gi += 28*256) {
      int t = gi, img, base, KT;
      if      (t < FF_OFF)  { img = 0; base = t - FQ_OFF;  KT = 5; }
      else if (t < FR_OFF)  { img = 1; base = t - FF_OFF;  KT = 7; }
      else if (t < FB_OFF)  { img = 2; base = t - FR_OFF;  KT = 4; }
      else if (t < FTQ_OFF) { img = 3; base = t - FB_OFF;  KT = 1; }
      else if (t < FTF_OFF) { img = 4; base = t - FTQ_OFF; KT = 2; }
      else                  { img = 5; base = t - FTF_OFF; KT = 2; }
      int j = base & 7, lane = (base >> 3) & 63, frag = base >> 9;
      int nt = frag / KT, kt = frag % KT;
      int k = kt*32 + ((lane >> 4) << 3) + j;
      int n = nt*16 + (lane & 15);
      float v = 0.f;
      if (img == 0) {
        if (n < ATT) {
          if (k < 128)      v = Wq[(80 + k)*ATT + n];
          else if (k < 148) v = Wq[(60 + (k - 128))*ATT + n];
        }
      } else if (img == 1) {
        if (k < 128)      v = Wff[(228 + k)*ALPHA + n];
        else if (k < 188) v = Wff[(k - 128)*ALPHA + n];
        else if (k < 208) v = Wff[(208 + (k - 188))*ALPHA + n];
      } else if (img == 2) {
        if (k < 128 && n < CTX) v = Wre[k*CTX + n];
      } else if (img == 3) {
        if (k < CTX && n < CTX) v = Wbc[k*CTX + n];
      } else if (img == 4) {
        if (n < ATT && k < 64)  v = Wq[(208 + k)*ATT + n];
      } else {
        if (k < 64)             v = Wff[(356 + k)*ALPHA + n];
      }
      pw[gi] = (fp16)v;
    }
  }
}

// ================= encode: ctxt + K + V, one batch elem per block =================
__global__ void dt_encode(const int* __restrict__ lemma,
    const float* __restrict__ Wb4, const float* __restrict__ bb4,
    const float* __restrict__ Waft, const float* __restrict__ baft,
    const float* __restrict__ Wall, const float* __restrict__ ball,
    char* __restrict__ ws) {
  __shared__ fp16 wkl[112*72];
  __shared__ float wb4[800], wa[400], wl[800];
  __shared__ float cel[LL*CTX], b4l[LL*CTX], afl[LL*CTX];
  __shared__ fp16 xin[LL*72];
  __shared__ float bi4[CTX], biA[CTX], biL[CTX];
  __shared__ int lem[52];
  const int b = blockIdx.x, tid = threadIdx.x;
  const fp16* ceg = (const fp16*)(ws + WS_TBL) + TBL_CE;
  const fp16* emg = (const fp16*)(ws + WS_TBL) + TBL_EM;

  { const uint4* s = (const uint4*)((const fp16*)(ws + WS_TBL) + TBL_WK);
    uint4* d = (uint4*)wkl;
    for (int i = tid; i < 112*72*2/16; i += 256) d[i] = s[i]; }
  { const float4* s = (const float4*)Wb4; float4* d = (float4*)wb4;
    for (int i = tid; i < 200; i += 256) d[i] = s[i]; }
  { const float4* s = (const float4*)Waft; float4* d = (float4*)wa;
    for (int i = tid; i < 100; i += 256) d[i] = s[i]; }
  { const float4* s = (const float4*)Wall; float4* d = (float4*)wl;
    for (int i = tid; i < 200; i += 256) d[i] = s[i]; }
  if (tid < CTX) { bi4[tid] = bb4[tid]; biA[tid] = baft[tid]; biL[tid] = ball[tid]; }
  if (tid < LL) lem[tid] = lemma[tid*BB + b];
  __syncthreads();

  for (int i = tid; i < LL*CTX; i += 256)
    cel[i] = (float)ceg[lem[i/CTX]*CTX + (i % CTX)];
  __syncthreads();

  for (int i = tid; i < LL*CTX; i += 256) {
    int l = i / CTX, o = i % CTX;
    float a = bi4[o];
    for (int c = 0; c < CTX; ++c) {
      float c2 = (l >= 2) ? cel[(l-2)*CTX + c] : 0.f;
      float c1 = (l >= 1) ? cel[(l-1)*CTX + c] : 0.f;
      a += c2*wb4[c*CTX + o] + c1*wb4[(CTX+c)*CTX + o];
    }
    b4l[i] = sigm(a);
    float af = biA[o];
    if (l < LL-1)
      for (int c = 0; c < CTX; ++c) af += cel[(l+1)*CTX + c]*wa[c*CTX + o];
    afl[i] = sigm(af);
  }
  __syncthreads();

  for (int i = tid; i < LL*CTX; i += 256) {
    int l = i / CTX, o = i % CTX;
    float a = biL[o];
    for (int c = 0; c < CTX; ++c)
      a += b4l[l*CTX + c]*wl[c*CTX + o] + afl[l*CTX + c]*wl[(CTX+c)*CTX + o];
    xin[l*72 + o] = (fp16)sigm(a);
  }
  for (int i = tid; i < LL*40; i += 256) {
    int l = i / 40, d = i % 40;
    xin[l*72 + 20 + d] = emg[lem[l]*40 + d];
  }
  for (int i = tid; i < LL*12; i += 256) {
    int l = i / 12, c = i % 12;
    xin[l*72 + 60 + c] = (fp16)0.f;
  }
  __syncthreads();

  const float* pkg = (const float*)(ws + WS_PK);
  fp16* Kw = (fp16*)(ws + WS_K) + (size_t)b*5200;
  for (int i = tid; i < 5200; i += 256) {
    int l = i / 104, a = i % 104;
    fp16 v = (fp16)0.f;
    if (a < ATT) {
      float acc = pkg[l*112 + a];
      const fp16* x = xin + l*72;
      const fp16* wv = wkl + a*72;
      #pragma unroll
      for (int k = 0; k < 9; ++k)
        acc = dot8f(*(const f16x8*)(x + 8*k), *(const f16x8*)(wv + 8*k), acc);
      v = (fp16)sigm(acc);
    }
    Kw[i] = v;
  }
  fp16* Vw = (fp16*)(ws + WS_V) + (size_t)b*3120;
  for (int i = tid; i < 3120; i += 256) {
    int d = i / 52, l = i % 52;
    Vw[i] = (l < LL) ? xin[l*72 + d] : (fp16)0.f;
  }
}

// ====== decoder: 7 elems/block, KW union (K rows | Wre+Wbc), V in LDS, ======
// ====== lgkm-only barriers, designed for <=128 VGPR -> 2 blocks/CU      ======
__global__ __launch_bounds__(512, 4)
void dt_decoder(const char* __restrict__ ws, const float* __restrict__ tags,
                const float* __restrict__ b_re, const float* __restrict__ b_bc,
                const float* __restrict__ bff, float* __restrict__ out) {
  extern __shared__ char sm[];
  fp16* Vl   = (fp16*)(sm + OFF_V);
  fp16* xq   = (fp16*)(sm + OFF_XQ);
  fp16* xf   = (fp16*)(sm + OFF_XF);
  fp16* rp   = (fp16*)(sm + OFF_RP);
  fp16* qb   = (fp16*)(sm + OFF_QB);
  fp16* sc   = (fp16*)(sm + OFF_SC);
  fp16* atb  = (fp16*)(sm + OFF_AT);
  fp16* tagq = (fp16*)(sm + OFF_TQ);
  fp16* tagf = (fp16*)(sm + OFF_TF);
  fp16* ctxs = (fp16*)(sm + OFF_CX);
  float* bbv = (float*)(sm + OFF_BB);
  fp16* tagsl = (fp16*)(sm + OFF_QB);   // prologue overlay on qb+sc (2304 <= 3776)

  const int tid = threadIdx.x, lane = tid & 63, w = tid >> 6;
  const int quad = lane >> 4, col = lane & 15;
  const int koff = quad * 8, r0 = quad * 4;
  const int b0 = blockIdx.x * EPB;
  const int nb = (BB - b0 < EPB) ? (BB - b0) : EPB;
  const bool bvalid = (w < EPB) && (w < nb);
  const int b = b0 + (bvalid ? w : 0);

  // ---- prologue: zero state ----
  { uint* z = (uint*)(sm + OFF_XQ);                 // xq|xf|rp contiguous
    for (int j = tid; j < (OFF_QB - OFF_XQ)/4; j += 512) z[j] = 0; }
  { uint* z = (uint*)(sm + OFF_AT);
    for (int j = tid; j < 832/4; j += 512) z[j] = 0; }
  { uint* z = (uint*)tagsl;
    for (int j = tid; j < 2304/4; j += 512) z[j] = 0; }

  // V stage: contiguous [b0 .. b0+nb) rows
  { const uint4* s = (const uint4*)(ws + WS_V + (size_t)b0*6240);
    uint4* d = (uint4*)Vl;
    for (int j = tid; j < nb*390; j += 512) d[j] = s[j]; }

  // biases
  if (tid < CTX) { bbv[tid] = b_re[tid]; bbv[20 + tid] = b_bc[tid]; }
  const float bffr = bff[w*16 + col];

  __syncthreads();   // tagsl zeros visible before fill (same region writers)

  // tags into tagsl rows 0..nb-1
  for (int j = tid; j < nb*64; j += 512) {
    int e = j >> 6, c = j & 63;
    tagsl[e*72 + c] = (fp16)tags[(size_t)(b0 + e)*64 + c];
  }
  // xq/xf init: one-hot probs + ctx(1) = sigm(b_bc)
  if (tid < EPB) { xq[tid*XQS + 1] = (fp16)1.f; xf[tid*XFS + 1] = (fp16)1.f; }
  if (tid < EPB*CTX) {
    int r = tid / CTX, o = tid % CTX;
    float c1 = sigm(b_bc[o]);
    xq[r*XQS + 128 + o] = (fp16)c1;
    xf[r*XFS + 188 + o] = (fp16)c1;
  }
  // out row 0
  for (int j = tid; j < nb*128; j += 512) {
    int e = j >> 7, o = j & 127;
    out[(size_t)(b0 + e)*ALPHA + o] = (o == 1) ? 1.f : 0.f;
  }
  __syncthreads();

  // ---- tag projections via MFMA (transient fragment regs) ----
  const fp16* fw = (const fp16*)(ws + WS_FRAG);
  {
    f16x8 a0 = *(const f16x8*)(tagsl + (lane & 15)*72 + koff);
    f16x8 a1 = *(const f16x8*)(tagsl + (lane & 15)*72 + 32 + koff);
    const int colg = w*16 + col;
    if (w < 7) {
      f16x8 t0 = *(const f16x8*)(fw + FTQ_OFF + (((w*2 + 0) << 6) + lane)*8);
      f16x8 t1 = *(const f16x8*)(fw + FTQ_OFF + (((w*2 + 1) << 6) + lane)*8);
      f32x4 c = {0.f,0.f,0.f,0.f};
      c = mfma16(a0, t0, c); c = mfma16(a1, t1, c);
      #pragma unroll
      for (int r = 0; r < 4; ++r) {
        int rr = r0 + r;
        if (rr < EPB && colg < 104) tagq[rr*TQS + colg] = (fp16)c[r];
      }
    }
    f16x8 u0 = *(const f16x8*)(fw + FTF_OFF + (((w*2 + 0) << 6) + lane)*8);
    f16x8 u1 = *(const f16x8*)(fw + FTF_OFF + (((w*2 + 1) << 6) + lane)*8);
    f32x4 d = {0.f,0.f,0.f,0.f};
    d = mfma16(a0, u0, d); d = mfma16(a1, u1, d);
    #pragma unroll
    for (int r = 0; r < 4; ++r) {
      int rr = r0 + r;
      if (rr < EPB) tagf[rr*128 + colg] = (fp16)(d[r] + bffr);
    }
  }

  // ---- persistent weights ----
  f16x8 wA[5], wB[7], KW[13];
  if (w < 7) {
    #pragma unroll
    for (int kt = 0; kt < 5; ++kt)
      wA[kt] = *(const f16x8*)(fw + FQ_OFF + (((w*5 + kt) << 6) + lane)*8);
    // K row for this wave's elem
    const int lrow = (lane < LL) ? lane : LL-1;
    const fp16* kg = (const fp16*)(ws + WS_K) + (size_t)b*5200 + lrow*104;
    #pragma unroll
    for (int j = 0; j < 13; ++j) KW[j] = *(const f16x8*)(kg + 8*j);
  } else {
    #pragma unroll
    for (int j = 0; j < 8; ++j)
      KW[j] = *(const f16x8*)(fw + FR_OFF + ((j << 6) + lane)*8);
    #pragma unroll
    for (int t = 0; t < 2; ++t)
      KW[8 + t] = *(const f16x8*)(fw + FB_OFF + ((t << 6) + lane)*8);
  }
  #pragma unroll
  for (int kt = 0; kt < 7; ++kt)
    wB[kt] = *(const f16x8*)(fw + FF_OFF + (((w*7 + kt) << 6) + lane)*8);

  const float* posqg = (const float*)(ws + WS_PQ);
  // per-lane LDS read bases (bytes via pointer arith on fp16*)
  const fp16* xq_a = xq + (lane & 15)*XQS + koff;
  const fp16* xf_a = xf + (lane & 15)*XFS + koff;
  const fp16* rp_a = rp + (lane & 15)*40 + koff;

  __syncthreads();

  // ==================== recurrence ====================
  for (int i = 1; i < LL; ++i) {
    // ---- Phase A ----
    if (w < 7) {
      const int colg = w*16 + col;
      float pos = posqg[i*112 + colg];
      f32x4 c0 = {0.f,0.f,0.f,0.f}, c1 = {0.f,0.f,0.f,0.f};
      c0 = mfma16(*(const f16x8*)(xq_a + 0*32),  wA[0], c0);
      c1 = mfma16(*(const f16x8*)(xq_a + 1*32),  wA[1], c1);
      c0 = mfma16(*(const f16x8*)(xq_a + 2*32),  wA[2], c0);
      c1 = mfma16(*(const f16x8*)(xq_a + 3*32),  wA[3], c1);
      c0 = mfma16(*(const f16x8*)(xq_a + 4*32),  wA[4], c0);
      if (r0 < 8 && colg < 104) {
        #pragma unroll
        for (int r = 0; r < 4; ++r) {
          int rr = r0 + r;
          if (rr < EPB)
            qb[rr*QBS + colg] = (fp16)sigm(c0[r] + c1[r] + pos + (float)tagq[rr*TQS + colg]);
        }
      }
    } else {
      // r(i-1) = sigm(probs(i-1) @ Wre + bre)
      f32x4 c0 = {0.f,0.f,0.f,0.f}, c1 = {0.f,0.f,0.f,0.f};
      #pragma unroll
      for (int kt = 0; kt < 4; ++kt) {
        f16x8 a = *(const f16x8*)(xq_a + kt*32);
        c0 = mfma16(a, KW[kt],     c0);
        c1 = mfma16(a, KW[4 + kt], c1);
      }
      const int cA = col, cB = 16 + col;
      if (r0 < 8) {
        #pragma unroll
        for (int r = 0; r < 4; ++r) {
          int rr = r0 + r;
          if (rr < EPB) {
            rp[rr*40 + cA] = (fp16)sigm(c0[r] + bbv[cA]);
            if (cB < CTX) rp[rr*40 + cB] = (fp16)sigm(c1[r] + bbv[cB]);
          }
        }
      }
      // ctx(i+1) = sigm(r(i-1) @ Wbc + bbc) -> staged to ctxs (copied in D)
      f16x8 ar = *(const f16x8*)rp_a;
      f32x4 d0 = mfma16(ar, KW[8], (f32x4){0.f,0.f,0.f,0.f});
      f32x4 d1 = mfma16(ar, KW[9], (f32x4){0.f,0.f,0.f,0.f});
      if (r0 < 8) {
        #pragma unroll
        for (int r = 0; r < 4; ++r) {
          int rr = r0 + r;
          if (rr < EPB) {
            ctxs[rr*20 + cA] = (fp16)sigm(d0[r] + bbv[20 + cA]);
            if (cB < CTX) ctxs[rr*20 + cB] = (fp16)sigm(d1[r] + bbv[20 + cB]);
          }
        }
      }
    }
    lbar();

    // ---- Phase B: scores, softmax-50, PV (wave e = w) ----
    if (w < 7) {
      const fp16* qrow = qb + w*QBS;
      float a0 = 0.f, a1 = 0.f;
      #pragma unroll
      for (int k = 0; k < 12; k += 2) {
        a0 = dot8f(*(const f16x8*)(qrow + 8*k),     KW[k],   a0);
        a1 = dot8f(*(const f16x8*)(qrow + 8*(k+1)), KW[k+1], a1);
      }
      a0 = dot8f(*(const f16x8*)(qrow + 96), KW[12], a0);
      float s = (lane < LL) ? (a0 + a1) : 0.f;     // scores >= 0
      float m  = redmax64(s);
      float e  = (lane < LL) ? __expf(s - m) : 0.f;
      float su = redsum64(e);
      if (lane < LL) atb[w*52 + lane] = (fp16)(e * rcpf(su));
      // PV: lane d reads V row d from LDS
      const fp16* ar = atb + w*52;
      const fp16* vr = Vl + (w*60 + ((lane < 60) ? lane : 59))*52;
      float v0 = 0.f, v1 = 0.f;
      #pragma unroll
      for (int k = 0; k < 12; k += 2) {
        v0 = dot4f(*(const f16x4*)(ar + 4*k),     *(const f16x4*)(vr + 4*k),     v0);
        v1 = dot4f(*(const f16x4*)(ar + 4*(k+1)), *(const f16x4*)(vr + 4*(k+1)), v1);
      }
      v0 = dot4f(*(const f16x4*)(ar + 48), *(const f16x4*)(vr + 48), v0);
      if (lane < 60) xf[w*XFS + 128 + lane] = (fp16)(v0 + v1);
    }
    lbar();

    // ---- Phase C: ff GEMM (all waves) ----
    {
      const int colg = w*16 + col;
      f32x4 c0 = {0.f,0.f,0.f,0.f}, c1 = {0.f,0.f,0.f,0.f};
      c0 = mfma16(*(const f16x8*)(xf_a + 0*32), wB[0], c0);
      c1 = mfma16(*(const f16x8*)(xf_a + 1*32), wB[1], c1);
      c0 = mfma16(*(const f16x8*)(xf_a + 2*32), wB[2], c0);
      c1 = mfma16(*(const f16x8*)(xf_a + 3*32), wB[3], c1);
      c0 = mfma16(*(const f16x8*)(xf_a + 4*32), wB[4], c0);
      c1 = mfma16(*(const f16x8*)(xf_a + 5*32), wB[5], c1);
      c0 = mfma16(*(const f16x8*)(xf_a + 6*32), wB[6], c0);
      if (r0 < 8) {
        #pragma unroll
        for (int r = 0; r < 4; ++r) {
          int rr = r0 + r;
          if (rr < EPB)
            sc[rr*SCS + colg] = (fp16)sigm(c0[r] + c1[r] + (float)tagf[rr*128 + colg]);
        }
      }
    }
    lbar();

    // ---- Phase D: softmax-128 + stores (waves 0-6); ctx copy (wave 7) ----
    if (w < 7) {
      float v0 = (float)sc[w*SCS + lane], v1 = (float)sc[w*SCS + 64 + lane];
      float m = redmax64(fmaxf(v0, v1));
      float e0 = __expf(v0 - m), e1 = __expf(v1 - m);
      float su = redsum64(e0 + e1);
      float inv = rcpf(su);
      float p0 = e0 * inv, p1 = e1 * inv;
      if (bvalid) {
        size_t ob = ((size_t)i*BB + b)*ALPHA;
        out[ob + lane] = p0; out[ob + 64 + lane] = p1;
      }
      xq[w*XQS + lane] = (fp16)p0; xq[w*XQS + 64 + lane] = (fp16)p1;
      xf[w*XFS + lane] = (fp16)p0; xf[w*XFS + 64 + lane] = (fp16)p1;
    } else if (lane < 56) {
      int r = lane >> 3, c8 = lane & 7;
      fp16 t0 = ctxs[r*20 + c8], t1 = ctxs[r*20 + 8 + c8];
      xq[r*XQS + 128 + c8] = t0; xq[r*XQS + 136 + c8] = t1;
      xf[r*XFS + 188 + c8] = t0; xf[r*XFS + 196 + c8] = t1;
      if (c8 < 4) {
        fp16 t2 = ctxs[r*20 + 16 + c8];
        xq[r*XQS + 144 + c8] = t2; xf[r*XFS + 204 + c8] = t2;
      }
    }
    lbar();
  }
}

extern "C" void kernel_launch(void* const* d_in, const int* in_sizes, int n_in,
                              void* d_out, int out_size, void* d_ws, size_t ws_size,
                              hipStream_t stream) {
  (void)in_sizes; (void)n_in; (void)out_size; (void)ws_size;
  const int*   lemma = (const int*)  d_in[0];
  const float* tags  = (const float*)d_in[1];
  const float* embT  = (const float*)d_in[2];
  const float* Wce   = (const float*)d_in[3];
  const float* bce   = (const float*)d_in[4];
  const float* Wb4   = (const float*)d_in[5];
  const float* bb4   = (const float*)d_in[6];
  const float* Waft  = (const float*)d_in[7];
  const float* baft  = (const float*)d_in[8];
  const float* Wall  = (const float*)d_in[9];
  const float* ball  = (const float*)d_in[10];
  const float* Wre   = (const float*)d_in[11];
  const float* bre   = (const float*)d_in[12];
  const float* Wbc   = (const float*)d_in[13];
  const float* bbc   = (const float*)d_in[14];
  const float* Wq    = (const float*)d_in[15];
  const float* bq    = (const float*)d_in[16];
  const float* Wk    = (const float*)d_in[17];
  const float* bk    = (const float*)d_in[18];
  const float* Wff   = (const float*)d_in[19];
  const float* bff   = (const float*)d_in[20];
  char* ws = (char*)d_ws;
  float* out = (float*)d_out;

  hipFuncSetAttribute((const void*)dt_decoder,
                      hipFuncAttributeMaxDynamicSharedMemorySize, SM_TOT);

  dt_setup<<<32, 256, 0, stream>>>(embT, Wce, bce, Wq, bq, Wk, bk, Wff, Wre, Wbc, ws);
  dt_encode<<<BB, 256, 0, stream>>>(lemma, Wb4, bb4, Waft, baft, Wall, ball, ws);
  dt_decoder<<<NBLK, 512, SM_TOT, stream>>>(ws, tags, bre, bbc, bff, out);
}

// Round 7
// 521.978 us; speedup vs baseline: 2.1250x; 2.1250x over previous
//
#include <hip/hip_runtime.h>

using fp16 = _Float16;
typedef fp16 f16x4 __attribute__((ext_vector_type(4)));
typedef fp16 f16x8 __attribute__((ext_vector_type(8)));
typedef float f32x4 __attribute__((ext_vector_type(4)));

#define DEVI __device__ __forceinline__

constexpr int LL = 50;
constexpr int BB = 4096;
constexpr int ALPHA = 128;
constexpr int CTX = 20;
constexpr int ATT = 100;
constexpr int EPB = 16;                   // elems per decoder block (fills MFMA M=16)

// ---- fragment image element offsets (fp16 elems) ----
constexpr int FQ_OFF  = 0;       // Wq_eff  [K=160][N=112]  NT=7 KT=5
constexpr int FF_OFF  = 17920;   // Wff_eff [K=224][N=128]  NT=8 KT=7
constexpr int FR_OFF  = 46592;   // Wre     [K=128][N=32]   NT=2 KT=4
constexpr int FB_OFF  = 50688;   // Wbc     [K=32][N=32]    NT=2 KT=1
constexpr int FTQ_OFF = 51712;   // Wq tag rows [64][112]   NT=7 KT=2
constexpr int FTF_OFF = 58880;   // Wff tag rows[64][128]   NT=8 KT=2
constexpr int FRAG_TOT= 67072;

// ---- workspace byte offsets ----
constexpr size_t WS_FRAG = 0;
constexpr size_t WS_PQ   = 134144;                     // f32 [50][112]
constexpr size_t WS_PK   = 156544;                     // f32 [50][112]
constexpr size_t WS_TBL  = 178944;                     // f16: ce|em|wk
constexpr int    TBL_CE  = 0;
constexpr int    TBL_EM  = 2560;
constexpr int    TBL_WK  = 7680;
constexpr int    TBL_N   = 15744;
constexpr size_t WS_K    = 210432;                     // f16 [4096][50][104]
constexpr size_t WS_V    = WS_K + (size_t)BB*5200*2;   // f16 [4096][60][52]

// ---- decoder LDS byte offsets (dynamic shared) ----
constexpr int XQS = 168, XFS = 232, QBS = 104, SCS = 136, TQS = 104, ATS = 56;
constexpr int OFF_XQ = 0;          // f16 [16][168] = 5376
constexpr int OFF_XF = 5376;       // f16 [16][232] = 7424
constexpr int OFF_RP = 12800;      // f16 [16][40]  = 1280
constexpr int OFF_QB = 14080;      // f16 [16][104] = 3328  (tagsl overlay in prologue)
constexpr int OFF_SC = 17408;      // f16 [16][136] = 4352
constexpr int OFF_AT = 21760;      // f16 [16][56]  = 1792
constexpr int OFF_TQ = 23552;      // f16 [16][104] = 3328
constexpr int OFF_TF = 26880;      // f16 [16][128] = 4096
constexpr int OFF_CX = 30976;      // f16 [16][20]  = 640
constexpr int OFF_BB = 31616;      // f32 [40]      = 160
constexpr int OFF_V  = 31776;      // f16 [16][60][52] = 99840
constexpr int SM_TOT = 131616;     // <= 163840 -> 1 block/CU, 16 waves

DEVI float rcpf(float x) { return __builtin_amdgcn_rcpf(x); }
DEVI float sigm(float x) { return rcpf(1.0f + __expf(-x)); }

DEVI f32x4 mfma16(f16x8 a, f16x8 b, f32x4 c) {
  return __builtin_amdgcn_mfma_f32_16x16x32_f16(a, b, c, 0, 0, 0);
}
DEVI float dot8f(f16x8 a, f16x8 b, float acc) {
  acc = __builtin_amdgcn_fdot2(__builtin_shufflevector(a,a,0,1), __builtin_shufflevector(b,b,0,1), acc, false);
  acc = __builtin_amdgcn_fdot2(__builtin_shufflevector(a,a,2,3), __builtin_shufflevector(b,b,2,3), acc, false);
  acc = __builtin_amdgcn_fdot2(__builtin_shufflevector(a,a,4,5), __builtin_shufflevector(b,b,4,5), acc, false);
  acc = __builtin_amdgcn_fdot2(__builtin_shufflevector(a,a,6,7), __builtin_shufflevector(b,b,6,7), acc, false);
  return acc;
}
DEVI float dot4f(f16x4 a, f16x4 b, float acc) {
  acc = __builtin_amdgcn_fdot2(__builtin_shufflevector(a,a,0,1), __builtin_shufflevector(b,b,0,1), acc, false);
  acc = __builtin_amdgcn_fdot2(__builtin_shufflevector(a,a,2,3), __builtin_shufflevector(b,b,2,3), acc, false);
  return acc;
}

// DPP all-VALU wave64 reductions. REQUIRES v >= 0 (bound_ctrl 0-fill safe).
#define DPP_STEP(OP, CTRL)                                                        \
  { int t_ = __builtin_amdgcn_update_dpp(0, __builtin_bit_cast(int, v), CTRL, 0xF, 0xF, true); \
    v = OP(v, __builtin_bit_cast(float, t_)); }
DEVI float addf(float a, float b) { return a + b; }
DEVI float redmax64(float v) {
  DPP_STEP(fmaxf, 0x111) DPP_STEP(fmaxf, 0x112) DPP_STEP(fmaxf, 0x114)
  DPP_STEP(fmaxf, 0x118) DPP_STEP(fmaxf, 0x142) DPP_STEP(fmaxf, 0x143)
  return __builtin_bit_cast(float, __builtin_amdgcn_readlane(__builtin_bit_cast(int, v), 63));
}
DEVI float redsum64(float v) {
  DPP_STEP(addf, 0x111) DPP_STEP(addf, 0x112) DPP_STEP(addf, 0x114)
  DPP_STEP(addf, 0x118) DPP_STEP(addf, 0x142) DPP_STEP(addf, 0x143)
  return __builtin_bit_cast(float, __builtin_amdgcn_readlane(__builtin_bit_cast(int, v), 63));
}

// LDS-only barrier: all cross-wave deps go through LDS; out-stores are wave-private.
DEVI void lbar() { asm volatile("s_waitcnt lgkmcnt(0)\ns_barrier" ::: "memory"); }

// ================= setup: tables + fragment-packed weights =================
__global__ void dt_setup(const float* __restrict__ embT, const float* __restrict__ Wce,
                         const float* __restrict__ bce,
                         const float* __restrict__ Wq, const float* __restrict__ bq,
                         const float* __restrict__ Wk, const float* __restrict__ bk,
                         const float* __restrict__ Wff, const float* __restrict__ Wre,
                         const float* __restrict__ Wbc, char* __restrict__ ws) {
  __shared__ float ap[LL*60];
  const int tid = threadIdx.x, bid = blockIdx.x;
  if (bid <= 1) {
    for (int i = tid; i < LL*30; i += 256) {
      int p = i / 30, k = i % 30;
      float freq = powf(10000.f, 2.0f*(float)k/60.0f);
      float ang = (float)p / freq;
      ap[p*60 + k]      = sinf(ang);
      ap[p*60 + 30 + k] = cosf(ang);
    }
    __syncthreads();
    const float* W = (bid == 0) ? Wq : Wk;
    const float* bi = (bid == 0) ? bq : bk;
    float* dst = (float*)(ws + (bid == 0 ? WS_PQ : WS_PK));
    for (int i = tid; i < LL*112; i += 256) {
      int r = i / 112, j = i % 112;
      float a = 0.f;
      if (j < ATT) {
        a = bi[j];
        for (int f = 0; f < 60; ++f) a += ap[r*60 + f]*W[f*ATT + j];
      }
      dst[i] = a;
    }
  } else if (bid == 2) {
    fp16* tbl = (fp16*)(ws + WS_TBL);
    for (int i = tid; i < ALPHA*CTX; i += 256) {
      int r = i / CTX, o = i % CTX;
      float a = bce[o];
      for (int e = 0; e < 40; ++e) a += embT[r*40 + e]*Wce[e*CTX + o];
      tbl[TBL_CE + i] = (fp16)a;
    }
    for (int i = tid; i < ALPHA*40; i += 256) tbl[TBL_EM + i] = (fp16)embT[i];
  } else if (bid == 3) {
    fp16* tbl = (fp16*)(ws + WS_TBL);
    for (int i = tid; i < 112*72; i += 256) {
      int a = i / 72, c = i % 72;
      float v = 0.f;
      if (a < ATT) {
        if (c < 20)      v = Wk[(60 + c)*ATT + a];
        else if (c < 60) v = Wk[(80 + (c-20))*ATT + a];
      }
      tbl[TBL_WK + i] = (fp16)v;
    }
  } else {
    fp16* pw = (fp16*)(ws + WS_FRAG);
    for (int gi = (bid-4)*256 + tid; gi < FRAG_TOT; gi += 28*256) {
      int t = gi, img, base, KT;
      if      (t < FF_OFF)  { img = 0; base = t - FQ_OFF;  KT = 5; }
      else if (t < FR_OFF)  { img = 1; base = t - FF_OFF;  KT = 7; }
      else if (t < FB_OFF)  { img = 2; base = t - FR_OFF;  KT = 4; }
      else if (t < FTQ_OFF) { img = 3; base = t - FB_OFF;  KT = 1; }
      else if (t < FTF_OFF) { img = 4; base = t - FTQ_OFF; KT = 2; }
      else                  { img = 5; base = t - FTF_OFF; KT = 2; }
      int j = base & 7, lane = (base >> 3) & 63, frag = base >> 9;
      int nt = frag / KT, kt = frag % KT;
      int k = kt*32 + ((lane >> 4) << 3) + j;
      int n = nt*16 + (lane & 15);
      float v = 0.f;
      if (img == 0) {
        if (n < ATT) {
          if (k < 128)      v = Wq[(80 + k)*ATT + n];
          else if (k < 148) v = Wq[(60 + (k - 128))*ATT + n];
        }
      } else if (img == 1) {
        if (k < 128)      v = Wff[(228 + k)*ALPHA + n];
        else if (k < 188) v = Wff[(k - 128)*ALPHA + n];
        else if (k < 208) v = Wff[(208 + (k - 188))*ALPHA + n];
      } else if (img == 2) {
        if (k < 128 && n < CTX) v = Wre[k*CTX + n];
      } else if (img == 3) {
        if (k < CTX && n < CTX) v = Wbc[k*CTX + n];
      } else if (img == 4) {
        if (n < ATT && k < 64)  v = Wq[(208 + k)*ATT + n];
      } else {
        if (k < 64)             v = Wff[(356 + k)*ALPHA + n];
      }
      pw[gi] = (fp16)v;
    }
  }
}

// ================= encode: ctxt + K + V, one batch elem per block =================
__global__ void dt_encode(const int* __restrict__ lemma,
    const float* __restrict__ Wb4, const float* __restrict__ bb4,
    const float* __restrict__ Waft, const float* __restrict__ baft,
    const float* __restrict__ Wall, const float* __restrict__ ball,
    char* __restrict__ ws) {
  __shared__ fp16 wkl[112*72];
  __shared__ float wb4[800], wa[400], wl[800];
  __shared__ float cel[LL*CTX], b4l[LL*CTX], afl[LL*CTX];
  __shared__ fp16 xin[LL*72];
  __shared__ float bi4[CTX], biA[CTX], biL[CTX];
  __shared__ int lem[52];
  const int b = blockIdx.x, tid = threadIdx.x;
  const fp16* ceg = (const fp16*)(ws + WS_TBL) + TBL_CE;
  const fp16* emg = (const fp16*)(ws + WS_TBL) + TBL_EM;

  { const uint4* s = (const uint4*)((const fp16*)(ws + WS_TBL) + TBL_WK);
    uint4* d = (uint4*)wkl;
    for (int i = tid; i < 112*72*2/16; i += 256) d[i] = s[i]; }
  { const float4* s = (const float4*)Wb4; float4* d = (float4*)wb4;
    for (int i = tid; i < 200; i += 256) d[i] = s[i]; }
  { const float4* s = (const float4*)Waft; float4* d = (float4*)wa;
    for (int i = tid; i < 100; i += 256) d[i] = s[i]; }
  { const float4* s = (const float4*)Wall; float4* d = (float4*)wl;
    for (int i = tid; i < 200; i += 256) d[i] = s[i]; }
  if (tid < CTX) { bi4[tid] = bb4[tid]; biA[tid] = baft[tid]; biL[tid] = ball[tid]; }
  if (tid < LL) lem[tid] = lemma[tid*BB + b];
  __syncthreads();

  for (int i = tid; i < LL*CTX; i += 256)
    cel[i] = (float)ceg[lem[i/CTX]*CTX + (i % CTX)];
  __syncthreads();

  for (int i = tid; i < LL*CTX; i += 256) {
    int l = i / CTX, o = i % CTX;
    float a = bi4[o];
    for (int c = 0; c < CTX; ++c) {
      float c2 = (l >= 2) ? cel[(l-2)*CTX + c] : 0.f;
      float c1 = (l >= 1) ? cel[(l-1)*CTX + c] : 0.f;
      a += c2*wb4[c*CTX + o] + c1*wb4[(CTX+c)*CTX + o];
    }
    b4l[i] = sigm(a);
    float af = biA[o];
    if (l < LL-1)
      for (int c = 0; c < CTX; ++c) af += cel[(l+1)*CTX + c]*wa[c*CTX + o];
    afl[i] = sigm(af);
  }
  __syncthreads();

  for (int i = tid; i < LL*CTX; i += 256) {
    int l = i / CTX, o = i % CTX;
    float a = biL[o];
    for (int c = 0; c < CTX; ++c)
      a += b4l[l*CTX + c]*wl[c*CTX + o] + afl[l*CTX + c]*wl[(CTX+c)*CTX + o];
    xin[l*72 + o] = (fp16)sigm(a);
  }
  for (int i = tid; i < LL*40; i += 256) {
    int l = i / 40, d = i % 40;
    xin[l*72 + 20 + d] = emg[lem[l]*40 + d];
  }
  for (int i = tid; i < LL*12; i += 256) {
    int l = i / 12, c = i % 12;
    xin[l*72 + 60 + c] = (fp16)0.f;
  }
  __syncthreads();

  const float* pkg = (const float*)(ws + WS_PK);
  fp16* Kw = (fp16*)(ws + WS_K) + (size_t)b*5200;
  for (int i = tid; i < 5200; i += 256) {
    int l = i / 104, a = i % 104;
    fp16 v = (fp16)0.f;
    if (a < ATT) {
      float acc = pkg[l*112 + a];
      const fp16* x = xin + l*72;
      const fp16* wv = wkl + a*72;
      #pragma unroll
      for (int k = 0; k < 9; ++k)
        acc = dot8f(*(const f16x8*)(x + 8*k), *(const f16x8*)(wv + 8*k), acc);
      v = (fp16)sigm(acc);
    }
    Kw[i] = v;
  }
  fp16* Vw = (fp16*)(ws + WS_V) + (size_t)b*3120;
  for (int i = tid; i < 3120; i += 256) {
    int d = i / 52, l = i % 52;
    Vw[i] = (l < LL) ? xin[l*72 + d] : (fp16)0.f;
  }
}

// ====== decoder: 16 elems/block, 16 waves, role-split weights, <=128 regs ======
// wave w: own elem's K row (KW, 52 regs) + role weights (wW, 40 regs):
//   w<7:  Wq N-tile w          (phase A q-GEMM)
//   w==7: Wre + Wbc            (phase A r/ctx-GEMM)
//   w>=8: Wff N-tile (w-8)     (phase C ff-GEMM)
__global__ __launch_bounds__(1024)
void dt_decoder(const char* __restrict__ ws, const float* __restrict__ tags,
                const float* __restrict__ b_re, const float* __restrict__ b_bc,
                const float* __restrict__ bff, float* __restrict__ out) {
  extern __shared__ char sm[];
  fp16* xq   = (fp16*)(sm + OFF_XQ);
  fp16* xf   = (fp16*)(sm + OFF_XF);
  fp16* rp   = (fp16*)(sm + OFF_RP);
  fp16* qb   = (fp16*)(sm + OFF_QB);
  fp16* sc   = (fp16*)(sm + OFF_SC);
  fp16* atb  = (fp16*)(sm + OFF_AT);
  fp16* tagq = (fp16*)(sm + OFF_TQ);
  fp16* tagf = (fp16*)(sm + OFF_TF);
  fp16* ctxs = (fp16*)(sm + OFF_CX);
  float* bbv = (float*)(sm + OFF_BB);
  fp16* Vl   = (fp16*)(sm + OFF_V);
  fp16* tagsl = (fp16*)(sm + OFF_QB);   // prologue overlay on qb (2304 <= 3328)

  const int tid = threadIdx.x, lane = tid & 63, w = tid >> 6;
  const int quad = lane >> 4, col = lane & 15;
  const int koff = quad * 8, r0 = quad * 4;
  const int b0 = blockIdx.x * EPB;
  const int b = b0 + w;                 // this wave's batch elem (always valid)

  // ---- prologue: zero state region [xq..atb] ----
  { uint* z = (uint*)sm;
    for (int j = tid; j < OFF_TQ/4; j += 1024) z[j] = 0; }
  // V stage: 16 elems, coalesced
  { const uint4* s = (const uint4*)(ws + WS_V + (size_t)b0*6240);
    uint4* d = (uint4*)Vl;
    for (int j = tid; j < EPB*390; j += 1024) d[j] = s[j]; }
  if (tid < CTX) { bbv[tid] = b_re[tid]; bbv[20 + tid] = b_bc[tid]; }
  const float bffr = bff[((w & 7) << 4) + col];
  __syncthreads();   // zeros (incl. tagsl overlay region) visible

  // tags into tagsl rows 0..15 (exactly 1024 values)
  { int e = tid >> 6, c = tid & 63;
    tagsl[e*72 + c] = (fp16)tags[(size_t)(b0 + e)*64 + c]; }
  if (tid < EPB) { xq[tid*XQS + 1] = (fp16)1.f; xf[tid*XFS + 1] = (fp16)1.f; }
  if (tid < EPB*CTX) {
    int r = tid / CTX, o = tid % CTX;
    float c1 = sigm(b_bc[o]);
    xq[r*XQS + 128 + o] = (fp16)c1;
    xf[r*XFS + 188 + o] = (fp16)c1;
  }
  for (int j = tid; j < EPB*128; j += 1024) {
    int e = j >> 7, o = j & 127;
    out[(size_t)(b0 + e)*ALPHA + o] = (o == 1) ? 1.f : 0.f;
  }
  __syncthreads();

  // ---- tag projections via MFMA (transient frag regs) ----
  const fp16* fw = (const fp16*)(ws + WS_FRAG);
  {
    f16x8 a0 = *(const f16x8*)(tagsl + (lane & 15)*72 + koff);
    f16x8 a1 = *(const f16x8*)(tagsl + (lane & 15)*72 + 32 + koff);
    if (w < 7) {
      f16x8 t0 = *(const f16x8*)(fw + FTQ_OFF + (((w*2 + 0) << 6) + lane)*8);
      f16x8 t1 = *(const f16x8*)(fw + FTQ_OFF + (((w*2 + 1) << 6) + lane)*8);
      f32x4 c = {0.f,0.f,0.f,0.f};
      c = mfma16(a0, t0, c); c = mfma16(a1, t1, c);
      const int colg = w*16 + col;
      if (colg < 104) {
        #pragma unroll
        for (int r = 0; r < 4; ++r) tagq[(r0 + r)*TQS + colg] = (fp16)c[r];
      }
    } else if (w >= 8) {
      f16x8 u0 = *(const f16x8*)(fw + FTF_OFF + ((((w-8)*2 + 0) << 6) + lane)*8);
      f16x8 u1 = *(const f16x8*)(fw + FTF_OFF + ((((w-8)*2 + 1) << 6) + lane)*8);
      f32x4 d = {0.f,0.f,0.f,0.f};
      d = mfma16(a0, u0, d); d = mfma16(a1, u1, d);
      const int colg = (w-8)*16 + col;
      #pragma unroll
      for (int r = 0; r < 4; ++r) tagf[(r0 + r)*128 + colg] = (fp16)(d[r] + bffr);
    }
  }

  // ---- persistent registers: K row (all waves) + role weights ----
  f16x8 KW[13], wW[10];
  { const int lrow = (lane < LL) ? lane : LL-1;
    const fp16* kg = (const fp16*)(ws + WS_K) + (size_t)b*5200 + lrow*104;
    #pragma unroll
    for (int j = 0; j < 13; ++j) KW[j] = *(const f16x8*)(kg + 8*j); }
  if (w < 7) {
    #pragma unroll
    for (int kt = 0; kt < 5; ++kt)
      wW[kt] = *(const f16x8*)(fw + FQ_OFF + (((w*5 + kt) << 6) + lane)*8);
  } else if (w == 7) {
    #pragma unroll
    for (int j = 0; j < 8; ++j)
      wW[j] = *(const f16x8*)(fw + FR_OFF + ((j << 6) + lane)*8);
    wW[8] = *(const f16x8*)(fw + FB_OFF + ((0 << 6) + lane)*8);
    wW[9] = *(const f16x8*)(fw + FB_OFF + ((1 << 6) + lane)*8);
  } else {
    #pragma unroll
    for (int kt = 0; kt < 7; ++kt)
      wW[kt] = *(const f16x8*)(fw + FF_OFF + ((((w-8)*7 + kt) << 6) + lane)*8);
  }

  const float* posqg = (const float*)(ws + WS_PQ);
  const fp16* xq_a = xq + (lane & 15)*XQS + koff;
  const fp16* xf_a = xf + (lane & 15)*XFS + koff;
  const fp16* rp_a = rp + (lane & 15)*40 + koff;

  __syncthreads();

  float pA = 0.f, pB = 0.f;   // previous step's probs (deferred out-store)

  // ==================== recurrence ====================
  for (int i = 1; i < LL; ++i) {
    // ---- Phase A: deferred store + q-GEMM (w<7) / r+ctx-GEMM (w==7) ----
    if (i > 1) {
      size_t ob = ((size_t)(i-1)*BB + b)*ALPHA;
      out[ob + lane] = pA; out[ob + 64 + lane] = pB;
    }
    if (w < 7) {
      const int colg = w*16 + col;
      float pos = posqg[i*112 + colg];
      f32x4 c0 = {0.f,0.f,0.f,0.f}, c1 = {0.f,0.f,0.f,0.f};
      c0 = mfma16(*(const f16x8*)(xq_a + 0*32), wW[0], c0);
      c1 = mfma16(*(const f16x8*)(xq_a + 1*32), wW[1], c1);
      c0 = mfma16(*(const f16x8*)(xq_a + 2*32), wW[2], c0);
      c1 = mfma16(*(const f16x8*)(xq_a + 3*32), wW[3], c1);
      c0 = mfma16(*(const f16x8*)(xq_a + 4*32), wW[4], c0);
      if (colg < 104) {
        #pragma unroll
        for (int r = 0; r < 4; ++r)
          qb[(r0 + r)*QBS + colg] =
            (fp16)sigm(c0[r] + c1[r] + pos + (float)tagq[(r0 + r)*TQS + colg]);
      }
    } else if (w == 7) {
      // r(i-1) = sigm(probs(i-1) @ Wre + bre), 16 elems at once
      f32x4 c0 = {0.f,0.f,0.f,0.f}, c1 = {0.f,0.f,0.f,0.f};
      #pragma unroll
      for (int kt = 0; kt < 4; ++kt) {
        f16x8 a = *(const f16x8*)(xq_a + kt*32);
        c0 = mfma16(a, wW[kt],     c0);
        c1 = mfma16(a, wW[4 + kt], c1);
      }
      const int cA = col, cB = 16 + col;
      #pragma unroll
      for (int r = 0; r < 4; ++r) {
        rp[(r0 + r)*40 + cA] = (fp16)sigm(c0[r] + bbv[cA]);
        if (cB < CTX) rp[(r0 + r)*40 + cB] = (fp16)sigm(c1[r] + bbv[cB]);
      }
      // ctx(i+1) = sigm(r(i-1) @ Wbc + bbc) -> staged (copied in phase D)
      f16x8 ar = *(const f16x8*)rp_a;
      f32x4 d0 = mfma16(ar, wW[8], (f32x4){0.f,0.f,0.f,0.f});
      f32x4 d1 = mfma16(ar, wW[9], (f32x4){0.f,0.f,0.f,0.f});
      #pragma unroll
      for (int r = 0; r < 4; ++r) {
        ctxs[(r0 + r)*20 + cA] = (fp16)sigm(d0[r] + bbv[20 + cA]);
        if (cB < CTX) ctxs[(r0 + r)*20 + cB] = (fp16)sigm(d1[r] + bbv[20 + cB]);
      }
    }
    lbar();

    // ---- Phase B (all waves, own elem): scores, softmax-50, PV ----
    {
      const fp16* qrow = qb + w*QBS;
      float a0 = 0.f, a1 = 0.f;
      #pragma unroll
      for (int k = 0; k < 12; k += 2) {
        a0 = dot8f(*(const f16x8*)(qrow + 8*k),     KW[k],   a0);
        a1 = dot8f(*(const f16x8*)(qrow + 8*(k+1)), KW[k+1], a1);
      }
      a0 = dot8f(*(const f16x8*)(qrow + 96), KW[12], a0);
      float s = (lane < LL) ? (a0 + a1) : 0.f;     // scores >= 0
      float m  = redmax64(s);
      float e  = (lane < LL) ? __expf(s - m) : 0.f;
      float su = redsum64(e);
      if (lane < LL) atb[w*ATS + lane] = (fp16)(e * rcpf(su));
      const fp16* ar = atb + w*ATS;
      const fp16* vr = Vl + (w*60 + ((lane < 60) ? lane : 59))*52;
      float v0 = 0.f, v1 = 0.f;
      #pragma unroll
      for (int k = 0; k < 12; k += 2) {
        v0 = dot4f(*(const f16x4*)(ar + 4*k),     *(const f16x4*)(vr + 4*k),     v0);
        v1 = dot4f(*(const f16x4*)(ar + 4*(k+1)), *(const f16x4*)(vr + 4*(k+1)), v1);
      }
      v0 = dot4f(*(const f16x4*)(ar + 48), *(const f16x4*)(vr + 48), v0);
      if (lane < 60) xf[w*XFS + 128 + lane] = (fp16)(v0 + v1);
    }
    lbar();

    // ---- Phase C (w>=8): ff-GEMM, 16 elems ----
    if (w >= 8) {
      const int colg = (w-8)*16 + col;
      f32x4 c0 = {0.f,0.f,0.f,0.f}, c1 = {0.f,0.f,0.f,0.f};
      c0 = mfma16(*(const f16x8*)(xf_a + 0*32), wW[0], c0);
      c1 = mfma16(*(const f16x8*)(xf_a + 1*32), wW[1], c1);
      c0 = mfma16(*(const f16x8*)(xf_a + 2*32), wW[2], c0);
      c1 = mfma16(*(const f16x8*)(xf_a + 3*32), wW[3], c1);
      c0 = mfma16(*(const f16x8*)(xf_a + 4*32), wW[4], c0);
      c1 = mfma16(*(const f16x8*)(xf_a + 5*32), wW[5], c1);
      c0 = mfma16(*(const f16x8*)(xf_a + 6*32), wW[6], c0);
      #pragma unroll
      for (int r = 0; r < 4; ++r)
        sc[(r0 + r)*SCS + colg] =
          (fp16)sigm(c0[r] + c1[r] + (float)tagf[(r0 + r)*128 + colg]);
    }
    lbar();

    // ---- Phase D (all waves, own elem): softmax-128; wave 7 also ctx copy ----
    {
      float v0 = (float)sc[w*SCS + lane], v1 = (float)sc[w*SCS + 64 + lane];
      float m = redmax64(fmaxf(v0, v1));
      float e0 = __expf(v0 - m), e1 = __expf(v1 - m);
      float su = redsum64(e0 + e1);
      float inv = rcpf(su);
      pA = e0 * inv; pB = e1 * inv;
      xq[w*XQS + lane] = (fp16)pA; xq[w*XQS + 64 + lane] = (fp16)pB;
      xf[w*XFS + lane] = (fp16)pA; xf[w*XFS + 64 + lane] = (fp16)pB;
    }
    if (w == 7) {
      int r = lane & 15, cg = (lane >> 4) * 5;
      #pragma unroll
      for (int j = 0; j < 5; ++j) {
        fp16 t = ctxs[r*20 + cg + j];
        xq[r*XQS + 128 + cg + j] = t;
        xf[r*XFS + 188 + cg + j] = t;
      }
    }
    lbar();
  }
  { size_t ob = ((size_t)(LL-1)*BB + b)*ALPHA;
    out[ob + lane] = pA; out[ob + 64 + lane] = pB; }
}

extern "C" void kernel_launch(void* const* d_in, const int* in_sizes, int n_in,
                              void* d_out, int out_size, void* d_ws, size_t ws_size,
                              hipStream_t stream) {
  (void)in_sizes; (void)n_in; (void)out_size; (void)ws_size;
  const int*   lemma = (const int*)  d_in[0];
  const float* tags  = (const float*)d_in[1];
  const float* embT  = (const float*)d_in[2];
  const float* Wce   = (const float*)d_in[3];
  const float* bce   = (const float*)d_in[4];
  const float* Wb4   = (const float*)d_in[5];
  const float* bb4   = (const float*)d_in[6];
  const float* Waft  = (const float*)d_in[7];
  const float* baft  = (const float*)d_in[8];
  const float* Wall  = (const float*)d_in[9];
  const float* ball  = (const float*)d_in[10];
  const float* Wre   = (const float*)d_in[11];
  const float* bre   = (const float*)d_in[12];
  const float* Wbc   = (const float*)d_in[13];
  const float* bbc   = (const float*)d_in[14];
  const float* Wq    = (const float*)d_in[15];
  const float* bq    = (const float*)d_in[16];
  const float* Wk    = (const float*)d_in[17];
  const float* bk    = (const float*)d_in[18];
  const float* Wff   = (const float*)d_in[19];
  const float* bff   = (const float*)d_in[20];
  char* ws = (char*)d_ws;
  float* out = (float*)d_out;

  hipFuncSetAttribute((const void*)dt_decoder,
                      hipFuncAttributeMaxDynamicSharedMemorySize, SM_TOT);

  dt_setup<<<32, 256, 0, stream>>>(embT, Wce, bce, Wq, bq, Wk, bk, Wff, Wre, Wbc, ws);
  dt_encode<<<BB, 256, 0, stream>>>(lemma, Wb4, bb4, Waft, baft, Wall, ball, ws);
  dt_decoder<<<BB/EPB, 1024, SM_TOT, stream>>>(ws, tags, bre, bbc, bff, out);
}

// Round 8
// 507.144 us; speedup vs baseline: 2.1872x; 1.0292x over previous
//
#include <hip/hip_runtime.h>

using fp16 = _Float16;
typedef fp16 f16x4 __attribute__((ext_vector_type(4)));
typedef fp16 f16x8 __attribute__((ext_vector_type(8)));
typedef float f32x4 __attribute__((ext_vector_type(4)));

#define DEVI __device__ __forceinline__

constexpr int LL = 50;
constexpr int BB = 4096;
constexpr int ALPHA = 128;
constexpr int CTX = 20;
constexpr int ATT = 100;
constexpr int EPB = 16;                   // elems per decoder block (fills MFMA M=16)

// ---- fragment image element offsets (fp16 elems) ----
constexpr int FQ_OFF  = 0;       // Wq_eff  [K=160][N=112]  NT=7 KT=5
constexpr int FF_OFF  = 17920;   // Wff_eff [K=224][N=128]  NT=8 KT=7
constexpr int FR_OFF  = 46592;   // Wre     [K=128][N=32]   NT=2 KT=4
constexpr int FB_OFF  = 50688;   // Wbc     [K=32][N=32]    NT=2 KT=1
constexpr int FTQ_OFF = 51712;   // Wq tag rows [64][112]   NT=7 KT=2
constexpr int FTF_OFF = 58880;   // Wff tag rows[64][128]   NT=8 KT=2
constexpr int FRAG_TOT= 67072;

// ---- workspace byte offsets ----
constexpr size_t WS_FRAG = 0;
constexpr size_t WS_PQ   = 134144;                     // f32 [50][112]
constexpr size_t WS_PK   = 156544;                     // f32 [50][112]
constexpr size_t WS_TBL  = 178944;                     // f16: ce|em|wk
constexpr int    TBL_CE  = 0;
constexpr int    TBL_EM  = 2560;
constexpr int    TBL_WK  = 7680;
constexpr int    TBL_N   = 15744;
constexpr size_t WS_K    = 210432;                     // f16 [4096][50][104]
constexpr size_t WS_V    = WS_K + (size_t)BB*5200*2;   // f16 [4096][60][52]

// ---- decoder LDS byte offsets (dynamic shared) ----
constexpr int XQS = 168, XFS = 232, QBS = 104, SCS = 136, TQS = 104, ATS = 56;
constexpr int OFF_XQ = 0;          // f16 [16][168] = 5376
constexpr int OFF_XF = 5376;       // f16 [16][232] = 7424
constexpr int OFF_RP = 12800;      // f16 [16][40]  = 1280
constexpr int OFF_QB = 14080;      // f16 [16][104] = 3328  (tagsl overlay in prologue)
constexpr int OFF_SC = 17408;      // f16 [16][136] = 4352
constexpr int OFF_AT = 21760;      // f16 [16][56]  = 1792
constexpr int OFF_TQ = 23552;      // f16 [16][104] = 3328
constexpr int OFF_TF = 26880;      // f16 [16][128] = 4096
constexpr int OFF_CX = 30976;      // f16 [16][20]  = 640
constexpr int OFF_BB = 31616;      // f32 [40]      = 160
constexpr int OFF_V  = 31776;      // f16 [16][60][52] = 99840
constexpr int OFF_WBC= 131616;     // f16 Wbc frags [2][64][8] = 2048
constexpr int SM_TOT = 133664;     // <= 163840 -> 1 block/CU, 16 waves

DEVI float rcpf(float x) { return __builtin_amdgcn_rcpf(x); }
DEVI float sigm(float x) { return rcpf(1.0f + __expf(-x)); }

DEVI f32x4 mfma16(f16x8 a, f16x8 b, f32x4 c) {
  return __builtin_amdgcn_mfma_f32_16x16x32_f16(a, b, c, 0, 0, 0);
}
DEVI float dot8f(f16x8 a, f16x8 b, float acc) {
  acc = __builtin_amdgcn_fdot2(__builtin_shufflevector(a,a,0,1), __builtin_shufflevector(b,b,0,1), acc, false);
  acc = __builtin_amdgcn_fdot2(__builtin_shufflevector(a,a,2,3), __builtin_shufflevector(b,b,2,3), acc, false);
  acc = __builtin_amdgcn_fdot2(__builtin_shufflevector(a,a,4,5), __builtin_shufflevector(b,b,4,5), acc, false);
  acc = __builtin_amdgcn_fdot2(__builtin_shufflevector(a,a,6,7), __builtin_shufflevector(b,b,6,7), acc, false);
  return acc;
}
DEVI float dot4f(f16x4 a, f16x4 b, float acc) {
  acc = __builtin_amdgcn_fdot2(__builtin_shufflevector(a,a,0,1), __builtin_shufflevector(b,b,0,1), acc, false);
  acc = __builtin_amdgcn_fdot2(__builtin_shufflevector(a,a,2,3), __builtin_shufflevector(b,b,2,3), acc, false);
  return acc;
}

// DPP all-VALU wave64 reductions. REQUIRES v >= 0 (bound_ctrl 0-fill safe).
#define DPP_STEP(OP, CTRL)                                                        \
  { int t_ = __builtin_amdgcn_update_dpp(0, __builtin_bit_cast(int, v), CTRL, 0xF, 0xF, true); \
    v = OP(v, __builtin_bit_cast(float, t_)); }
DEVI float addf(float a, float b) { return a + b; }
DEVI float redmax64(float v) {
  DPP_STEP(fmaxf, 0x111) DPP_STEP(fmaxf, 0x112) DPP_STEP(fmaxf, 0x114)
  DPP_STEP(fmaxf, 0x118) DPP_STEP(fmaxf, 0x142) DPP_STEP(fmaxf, 0x143)
  return __builtin_bit_cast(float, __builtin_amdgcn_readlane(__builtin_bit_cast(int, v), 63));
}
DEVI float redsum64(float v) {
  DPP_STEP(addf, 0x111) DPP_STEP(addf, 0x112) DPP_STEP(addf, 0x114)
  DPP_STEP(addf, 0x118) DPP_STEP(addf, 0x142) DPP_STEP(addf, 0x143)
  return __builtin_bit_cast(float, __builtin_amdgcn_readlane(__builtin_bit_cast(int, v), 63));
}

// LDS-only barrier: all cross-wave deps go through LDS; out-stores are wave-private.
DEVI void lbar() { asm volatile("s_waitcnt lgkmcnt(0)\ns_barrier" ::: "memory"); }

// ================= setup: tables + fragment-packed weights =================
__global__ void dt_setup(const float* __restrict__ embT, const float* __restrict__ Wce,
                         const float* __restrict__ bce,
                         const float* __restrict__ Wq, const float* __restrict__ bq,
                         const float* __restrict__ Wk, const float* __restrict__ bk,
                         const float* __restrict__ Wff, const float* __restrict__ Wre,
                         const float* __restrict__ Wbc, char* __restrict__ ws) {
  __shared__ float ap[LL*60];
  const int tid = threadIdx.x, bid = blockIdx.x;
  if (bid <= 1) {
    for (int i = tid; i < LL*30; i += 256) {
      int p = i / 30, k = i % 30;
      float freq = powf(10000.f, 2.0f*(float)k/60.0f);
      float ang = (float)p / freq;
      ap[p*60 + k]      = sinf(ang);
      ap[p*60 + 30 + k] = cosf(ang);
    }
    __syncthreads();
    const float* W = (bid == 0) ? Wq : Wk;
    const float* bi = (bid == 0) ? bq : bk;
    float* dst = (float*)(ws + (bid == 0 ? WS_PQ : WS_PK));
    for (int i = tid; i < LL*112; i += 256) {
      int r = i / 112, j = i % 112;
      float a = 0.f;
      if (j < ATT) {
        a = bi[j];
        for (int f = 0; f < 60; ++f) a += ap[r*60 + f]*W[f*ATT + j];
      }
      dst[i] = a;
    }
  } else if (bid == 2) {
    fp16* tbl = (fp16*)(ws + WS_TBL);
    for (int i = tid; i < ALPHA*CTX; i += 256) {
      int r = i / CTX, o = i % CTX;
      float a = bce[o];
      for (int e = 0; e < 40; ++e) a += embT[r*40 + e]*Wce[e*CTX + o];
      tbl[TBL_CE + i] = (fp16)a;
    }
    for (int i = tid; i < ALPHA*40; i += 256) tbl[TBL_EM + i] = (fp16)embT[i];
  } else if (bid == 3) {
    fp16* tbl = (fp16*)(ws + WS_TBL);
    for (int i = tid; i < 112*72; i += 256) {
      int a = i / 72, c = i % 72;
      float v = 0.f;
      if (a < ATT) {
        if (c < 20)      v = Wk[(60 + c)*ATT + a];
        else if (c < 60) v = Wk[(80 + (c-20))*ATT + a];
      }
      tbl[TBL_WK + i] = (fp16)v;
    }
  } else {
    fp16* pw = (fp16*)(ws + WS_FRAG);
    for (int gi = (bid-4)*256 + tid; gi < FRAG_TOT; gi += 28*256) {
      int t = gi, img, base, KT;
      if      (t < FF_OFF)  { img = 0; base = t - FQ_OFF;  KT = 5; }
      else if (t < FR_OFF)  { img = 1; base = t - FF_OFF;  KT = 7; }
      else if (t < FB_OFF)  { img = 2; base = t - FR_OFF;  KT = 4; }
      else if (t < FTQ_OFF) { img = 3; base = t - FB_OFF;  KT = 1; }
      else if (t < FTF_OFF) { img = 4; base = t - FTQ_OFF; KT = 2; }
      else                  { img = 5; base = t - FTF_OFF; KT = 2; }
      int j = base & 7, lane = (base >> 3) & 63, frag = base >> 9;
      int nt = frag / KT, kt = frag % KT;
      int k = kt*32 + ((lane >> 4) << 3) + j;
      int n = nt*16 + (lane & 15);
      float v = 0.f;
      if (img == 0) {
        if (n < ATT) {
          if (k < 128)      v = Wq[(80 + k)*ATT + n];
          else if (k < 148) v = Wq[(60 + (k - 128))*ATT + n];
        }
      } else if (img == 1) {
        if (k < 128)      v = Wff[(228 + k)*ALPHA + n];
        else if (k < 188) v = Wff[(k - 128)*ALPHA + n];
        else if (k < 208) v = Wff[(208 + (k - 188))*ALPHA + n];
      } else if (img == 2) {
        if (k < 128 && n < CTX) v = Wre[k*CTX + n];
      } else if (img == 3) {
        if (k < CTX && n < CTX) v = Wbc[k*CTX + n];
      } else if (img == 4) {
        if (n < ATT && k < 64)  v = Wq[(208 + k)*ATT + n];
      } else {
        if (k < 64)             v = Wff[(356 + k)*ALPHA + n];
      }
      pw[gi] = (fp16)v;
    }
  }
}

// ================= encode: ctxt + K + V, one batch elem per block =================
__global__ void dt_encode(const int* __restrict__ lemma,
    const float* __restrict__ Wb4, const float* __restrict__ bb4,
    const float* __restrict__ Waft, const float* __restrict__ baft,
    const float* __restrict__ Wall, const float* __restrict__ ball,
    char* __restrict__ ws) {
  __shared__ fp16 wkl[112*72];
  __shared__ float wb4[800], wa[400], wl[800];
  __shared__ float cel[LL*CTX], b4l[LL*CTX], afl[LL*CTX];
  __shared__ fp16 xin[LL*72];
  __shared__ float bi4[CTX], biA[CTX], biL[CTX];
  __shared__ int lem[52];
  const int b = blockIdx.x, tid = threadIdx.x;
  const fp16* ceg = (const fp16*)(ws + WS_TBL) + TBL_CE;
  const fp16* emg = (const fp16*)(ws + WS_TBL) + TBL_EM;

  { const uint4* s = (const uint4*)((const fp16*)(ws + WS_TBL) + TBL_WK);
    uint4* d = (uint4*)wkl;
    for (int i = tid; i < 112*72*2/16; i += 256) d[i] = s[i]; }
  { const float4* s = (const float4*)Wb4; float4* d = (float4*)wb4;
    for (int i = tid; i < 200; i += 256) d[i] = s[i]; }
  { const float4* s = (const float4*)Waft; float4* d = (float4*)wa;
    for (int i = tid; i < 100; i += 256) d[i] = s[i]; }
  { const float4* s = (const float4*)Wall; float4* d = (float4*)wl;
    for (int i = tid; i < 200; i += 256) d[i] = s[i]; }
  if (tid < CTX) { bi4[tid] = bb4[tid]; biA[tid] = baft[tid]; biL[tid] = ball[tid]; }
  if (tid < LL) lem[tid] = lemma[tid*BB + b];
  __syncthreads();

  for (int i = tid; i < LL*CTX; i += 256)
    cel[i] = (float)ceg[lem[i/CTX]*CTX + (i % CTX)];
  __syncthreads();

  for (int i = tid; i < LL*CTX; i += 256) {
    int l = i / CTX, o = i % CTX;
    float a = bi4[o];
    for (int c = 0; c < CTX; ++c) {
      float c2 = (l >= 2) ? cel[(l-2)*CTX + c] : 0.f;
      float c1 = (l >= 1) ? cel[(l-1)*CTX + c] : 0.f;
      a += c2*wb4[c*CTX + o] + c1*wb4[(CTX+c)*CTX + o];
    }
    b4l[i] = sigm(a);
    float af = biA[o];
    if (l < LL-1)
      for (int c = 0; c < CTX; ++c) af += cel[(l+1)*CTX + c]*wa[c*CTX + o];
    afl[i] = sigm(af);
  }
  __syncthreads();

  for (int i = tid; i < LL*CTX; i += 256) {
    int l = i / CTX, o = i % CTX;
    float a = biL[o];
    for (int c = 0; c < CTX; ++c)
      a += b4l[l*CTX + c]*wl[c*CTX + o] + afl[l*CTX + c]*wl[(CTX+c)*CTX + o];
    xin[l*72 + o] = (fp16)sigm(a);
  }
  for (int i = tid; i < LL*40; i += 256) {
    int l = i / 40, d = i % 40;
    xin[l*72 + 20 + d] = emg[lem[l]*40 + d];
  }
  for (int i = tid; i < LL*12; i += 256) {
    int l = i / 12, c = i % 12;
    xin[l*72 + 60 + c] = (fp16)0.f;
  }
  __syncthreads();

  const float* pkg = (const float*)(ws + WS_PK);
  fp16* Kw = (fp16*)(ws + WS_K) + (size_t)b*5200;
  for (int i = tid; i < 5200; i += 256) {
    int l = i / 104, a = i % 104;
    fp16 v = (fp16)0.f;
    if (a < ATT) {
      float acc = pkg[l*112 + a];
      const fp16* x = xin + l*72;
      const fp16* wv = wkl + a*72;
      #pragma unroll
      for (int k = 0; k < 9; ++k)
        acc = dot8f(*(const f16x8*)(x + 8*k), *(const f16x8*)(wv + 8*k), acc);
      v = (fp16)sigm(acc);
    }
    Kw[i] = v;
  }
  fp16* Vw = (fp16*)(ws + WS_V) + (size_t)b*3120;
  for (int i = tid; i < 3120; i += 256) {
    int d = i / 52, l = i % 52;
    Vw[i] = (l < LL) ? xin[l*72 + d] : (fp16)0.f;
  }
}

// ====== decoder: 16 elems/block, 16 waves, role-split weights ======
// __launch_bounds__(1024, 1): 1 block/CU -> 16 waves/CU -> 128-VGPR cap,
// and compiler targets 128 (not 64) so the ~90-reg persistent state fits.
// wave w roles: w<7 Wq-tile | w==7 Wre (Wbc via LDS) | w>=8 Wff-tile.
__global__ __launch_bounds__(1024, 1)
void dt_decoder(const char* __restrict__ ws, const float* __restrict__ tags,
                const float* __restrict__ b_re, const float* __restrict__ b_bc,
                const float* __restrict__ bff, float* __restrict__ out) {
  extern __shared__ char sm[];
  fp16* xq   = (fp16*)(sm + OFF_XQ);
  fp16* xf   = (fp16*)(sm + OFF_XF);
  fp16* rp   = (fp16*)(sm + OFF_RP);
  fp16* qb   = (fp16*)(sm + OFF_QB);
  fp16* sc   = (fp16*)(sm + OFF_SC);
  fp16* atb  = (fp16*)(sm + OFF_AT);
  fp16* tagq = (fp16*)(sm + OFF_TQ);
  fp16* tagf = (fp16*)(sm + OFF_TF);
  fp16* ctxs = (fp16*)(sm + OFF_CX);
  float* bbv = (float*)(sm + OFF_BB);
  fp16* Vl   = (fp16*)(sm + OFF_V);
  fp16* wbcl = (fp16*)(sm + OFF_WBC);
  fp16* tagsl = (fp16*)(sm + OFF_QB);   // prologue overlay on qb (2304 <= 3328)

  const int tid = threadIdx.x, lane = tid & 63, w = tid >> 6;
  const int quad = lane >> 4, col = lane & 15;
  const int koff = quad * 8, r0 = quad * 4;
  const int b0 = blockIdx.x * EPB;
  const int b = b0 + w;                 // this wave's batch elem

  // ---- prologue: zero state region [xq..atb] ----
  { uint* z = (uint*)sm;
    for (int j = tid; j < OFF_TQ/4; j += 1024) z[j] = 0; }
  // V stage: 16 elems, coalesced
  { const uint4* s = (const uint4*)(ws + WS_V + (size_t)b0*6240);
    uint4* d = (uint4*)Vl;
    for (int j = tid; j < EPB*390; j += 1024) d[j] = s[j]; }
  if (tid < CTX) { bbv[tid] = b_re[tid]; bbv[20 + tid] = b_bc[tid]; }
  const float bffr = bff[((w & 7) << 4) + col];
  __syncthreads();   // zeros (incl. tagsl overlay region) visible

  // tags into tagsl rows 0..15 (exactly 1024 values)
  { int e = tid >> 6, c = tid & 63;
    tagsl[e*72 + c] = (fp16)tags[(size_t)(b0 + e)*64 + c]; }
  if (tid < EPB) { xq[tid*XQS + 1] = (fp16)1.f; xf[tid*XFS + 1] = (fp16)1.f; }
  if (tid < EPB*CTX) {
    int r = tid / CTX, o = tid % CTX;
    float c1 = sigm(b_bc[o]);
    xq[r*XQS + 128 + o] = (fp16)c1;
    xf[r*XFS + 188 + o] = (fp16)c1;
  }
  for (int j = tid; j < EPB*128; j += 1024) {
    int e = j >> 7, o = j & 127;
    out[(size_t)(b0 + e)*ALPHA + o] = (o == 1) ? 1.f : 0.f;
  }
  __syncthreads();

  // ---- tag projections via MFMA (transient frag regs) ----
  const fp16* fw = (const fp16*)(ws + WS_FRAG);
  {
    f16x8 a0 = *(const f16x8*)(tagsl + (lane & 15)*72 + koff);
    f16x8 a1 = *(const f16x8*)(tagsl + (lane & 15)*72 + 32 + koff);
    if (w < 7) {
      f16x8 t0 = *(const f16x8*)(fw + FTQ_OFF + (((w*2 + 0) << 6) + lane)*8);
      f16x8 t1 = *(const f16x8*)(fw + FTQ_OFF + (((w*2 + 1) << 6) + lane)*8);
      f32x4 c = {0.f,0.f,0.f,0.f};
      c = mfma16(a0, t0, c); c = mfma16(a1, t1, c);
      const int colg = w*16 + col;
      if (colg < 104) {
        #pragma unroll
        for (int r = 0; r < 4; ++r) tagq[(r0 + r)*TQS + colg] = (fp16)c[r];
      }
    } else if (w >= 8) {
      f16x8 u0 = *(const f16x8*)(fw + FTF_OFF + ((((w-8)*2 + 0) << 6) + lane)*8);
      f16x8 u1 = *(const f16x8*)(fw + FTF_OFF + ((((w-8)*2 + 1) << 6) + lane)*8);
      f32x4 d = {0.f,0.f,0.f,0.f};
      d = mfma16(a0, u0, d); d = mfma16(a1, u1, d);
      const int colg = (w-8)*16 + col;
      #pragma unroll
      for (int r = 0; r < 4; ++r) tagf[(r0 + r)*128 + colg] = (fp16)(d[r] + bffr);
    }
  }

  // ---- persistent registers: K row (all waves) + role weights (max 8 frags) ----
  f16x8 KW[13], wW[8];
  { const int lrow = (lane < LL) ? lane : LL-1;
    const fp16* kg = (const fp16*)(ws + WS_K) + (size_t)b*5200 + lrow*104;
    #pragma unroll
    for (int j = 0; j < 13; ++j) KW[j] = *(const f16x8*)(kg + 8*j); }
  if (w < 7) {
    #pragma unroll
    for (int kt = 0; kt < 5; ++kt)
      wW[kt] = *(const f16x8*)(fw + FQ_OFF + (((w*5 + kt) << 6) + lane)*8);
  } else if (w == 7) {
    #pragma unroll
    for (int j = 0; j < 8; ++j)
      wW[j] = *(const f16x8*)(fw + FR_OFF + ((j << 6) + lane)*8);
    // Wbc frags -> LDS (read back per step; wave-private region)
    #pragma unroll
    for (int t = 0; t < 2; ++t) {
      f16x8 v = *(const f16x8*)(fw + FB_OFF + ((t << 6) + lane)*8);
      *(f16x8*)(wbcl + ((t << 6) + lane)*8) = v;
    }
  } else {
    #pragma unroll
    for (int kt = 0; kt < 7; ++kt)
      wW[kt] = *(const f16x8*)(fw + FF_OFF + ((((w-8)*7 + kt) << 6) + lane)*8);
  }

  const float* posqg = (const float*)(ws + WS_PQ);
  const fp16* xq_a = xq + (lane & 15)*XQS + koff;
  const fp16* xf_a = xf + (lane & 15)*XFS + koff;
  const fp16* rp_a = rp + (lane & 15)*40 + koff;

  __syncthreads();

  float pA = 0.f, pB = 0.f;   // previous step's probs (deferred out-store)

  // ==================== recurrence ====================
  for (int i = 1; i < LL; ++i) {
    // ---- Phase A: deferred store + q-GEMM (w<7) / r+ctx-GEMM (w==7) ----
    if (i > 1) {
      size_t ob = ((size_t)(i-1)*BB + b)*ALPHA;
      out[ob + lane] = pA; out[ob + 64 + lane] = pB;
    }
    if (w < 7) {
      const int colg = w*16 + col;
      float pos = posqg[i*112 + colg];
      f32x4 c0 = {0.f,0.f,0.f,0.f}, c1 = {0.f,0.f,0.f,0.f};
      c0 = mfma16(*(const f16x8*)(xq_a + 0*32), wW[0], c0);
      c1 = mfma16(*(const f16x8*)(xq_a + 1*32), wW[1], c1);
      c0 = mfma16(*(const f16x8*)(xq_a + 2*32), wW[2], c0);
      c1 = mfma16(*(const f16x8*)(xq_a + 3*32), wW[3], c1);
      c0 = mfma16(*(const f16x8*)(xq_a + 4*32), wW[4], c0);
      if (colg < 104) {
        #pragma unroll
        for (int r = 0; r < 4; ++r)
          qb[(r0 + r)*QBS + colg] =
            (fp16)sigm(c0[r] + c1[r] + pos + (float)tagq[(r0 + r)*TQS + colg]);
      }
    } else if (w == 7) {
      // r(i-1) = sigm(probs(i-1) @ Wre + bre), 16 elems at once
      f32x4 c0 = {0.f,0.f,0.f,0.f}, c1 = {0.f,0.f,0.f,0.f};
      #pragma unroll
      for (int kt = 0; kt < 4; ++kt) {
        f16x8 a = *(const f16x8*)(xq_a + kt*32);
        c0 = mfma16(a, wW[kt],     c0);
        c1 = mfma16(a, wW[4 + kt], c1);
      }
      const int cA = col, cB = 16 + col;
      #pragma unroll
      for (int r = 0; r < 4; ++r) {
        rp[(r0 + r)*40 + cA] = (fp16)sigm(c0[r] + bbv[cA]);
        if (cB < CTX) rp[(r0 + r)*40 + cB] = (fp16)sigm(c1[r] + bbv[cB]);
      }
      // ctx(i+1) = sigm(r(i-1) @ Wbc + bbc) -> staged (copied in phase D)
      f16x8 ar = *(const f16x8*)rp_a;
      f16x8 wb0 = *(const f16x8*)(wbcl + ((0 << 6) + lane)*8);
      f16x8 wb1 = *(const f16x8*)(wbcl + ((1 << 6) + lane)*8);
      f32x4 d0 = mfma16(ar, wb0, (f32x4){0.f,0.f,0.f,0.f});
      f32x4 d1 = mfma16(ar, wb1, (f32x4){0.f,0.f,0.f,0.f});
      #pragma unroll
      for (int r = 0; r < 4; ++r) {
        ctxs[(r0 + r)*20 + cA] = (fp16)sigm(d0[r] + bbv[20 + cA]);
        if (cB < CTX) ctxs[(r0 + r)*20 + cB] = (fp16)sigm(d1[r] + bbv[20 + cB]);
      }
    }
    lbar();

    // ---- Phase B (all waves, own elem): scores, softmax-50, PV ----
    {
      const fp16* qrow = qb + w*QBS;
      float a0 = 0.f, a1 = 0.f;
      #pragma unroll
      for (int k = 0; k < 12; k += 2) {
        a0 = dot8f(*(const f16x8*)(qrow + 8*k),     KW[k],   a0);
        a1 = dot8f(*(const f16x8*)(qrow + 8*(k+1)), KW[k+1], a1);
      }
      a0 = dot8f(*(const f16x8*)(qrow + 96), KW[12], a0);
      float s = (lane < LL) ? (a0 + a1) : 0.f;     // scores >= 0
      float m  = redmax64(s);
      float e  = (lane < LL) ? __expf(s - m) : 0.f;
      float su = redsum64(e);
      if (lane < LL) atb[w*ATS + lane] = (fp16)(e * rcpf(su));
      const fp16* ar = atb + w*ATS;
      const fp16* vr = Vl + (w*60 + ((lane < 60) ? lane : 59))*52;
      float v0 = 0.f, v1 = 0.f;
      #pragma unroll
      for (int k = 0; k < 12; k += 2) {
        v0 = dot4f(*(const f16x4*)(ar + 4*k),     *(const f16x4*)(vr + 4*k),     v0);
        v1 = dot4f(*(const f16x4*)(ar + 4*(k+1)), *(const f16x4*)(vr + 4*(k+1)), v1);
      }
      v0 = dot4f(*(const f16x4*)(ar + 48), *(const f16x4*)(vr + 48), v0);
      if (lane < 60) xf[w*XFS + 128 + lane] = (fp16)(v0 + v1);
    }
    lbar();

    // ---- Phase C (w>=8): ff-GEMM, 16 elems ----
    if (w >= 8) {
      const int colg = (w-8)*16 + col;
      f32x4 c0 = {0.f,0.f,0.f,0.f}, c1 = {0.f,0.f,0.f,0.f};
      c0 = mfma16(*(const f16x8*)(xf_a + 0*32), wW[0], c0);
      c1 = mfma16(*(const f16x8*)(xf_a + 1*32), wW[1], c1);
      c0 = mfma16(*(const f16x8*)(xf_a + 2*32), wW[2], c0);
      c1 = mfma16(*(const f16x8*)(xf_a + 3*32), wW[3], c1);
      c0 = mfma16(*(const f16x8*)(xf_a + 4*32), wW[4], c0);
      c1 = mfma16(*(const f16x8*)(xf_a + 5*32), wW[5], c1);
      c0 = mfma16(*(const f16x8*)(xf_a + 6*32), wW[6], c0);
      #pragma unroll
      for (int r = 0; r < 4; ++r)
        sc[(r0 + r)*SCS + colg] =
          (fp16)sigm(c0[r] + c1[r] + (float)tagf[(r0 + r)*128 + colg]);
    }
    lbar();

    // ---- Phase D (all waves, own elem): softmax-128; wave 7 also ctx copy ----
    {
      float v0 = (float)sc[w*SCS + lane], v1 = (float)sc[w*SCS + 64 + lane];
      float m = redmax64(fmaxf(v0, v1));
      float e0 = __expf(v0 - m), e1 = __expf(v1 - m);
      float su = redsum64(e0 + e1);
      float inv = rcpf(su);
      pA = e0 * inv; pB = e1 * inv;
      xq[w*XQS + lane] = (fp16)pA; xq[w*XQS + 64 + lane] = (fp16)pB;
      xf[w*XFS + lane] = (fp16)pA; xf[w*XFS + 64 + lane] = (fp16)pB;
    }
    if (w == 7) {
      int r = lane & 15, cg = (lane >> 4) * 5;
      #pragma unroll
      for (int j = 0; j < 5; ++j) {
        fp16 t = ctxs[r*20 + cg + j];
        xq[r*XQS + 128 + cg + j] = t;
        xf[r*XFS + 188 + cg + j] = t;
      }
    }
    lbar();
  }
  { size_t ob = ((size_t)(LL-1)*BB + b)*ALPHA;
    out[ob + lane] = pA; out[ob + 64 + lane] = pB; }
}

extern "C" void kernel_launch(void* const* d_in, const int* in_sizes, int n_in,
                              void* d_out, int out_size, void* d_ws, size_t ws_size,
                              hipStream_t stream) {
  (void)in_sizes; (void)n_in; (void)out_size; (void)ws_size;
  const int*   lemma = (const int*)  d_in[0];
  const float* tags  = (const float*)d_in[1];
  const float* embT  = (const float*)d_in[2];
  const float* Wce   = (const float*)d_in[3];
  const float* bce   = (const float*)d_in[4];
  const float* Wb4   = (const float*)d_in[5];
  const float* bb4   = (const float*)d_in[6];
  const float* Waft  = (const float*)d_in[7];
  const float* baft  = (const float*)d_in[8];
  const float* Wall  = (const float*)d_in[9];
  const float* ball  = (const float*)d_in[10];
  const float* Wre   = (const float*)d_in[11];
  const float* bre   = (const float*)d_in[12];
  const float* Wbc   = (const float*)d_in[13];
  const float* bbc   = (const float*)d_in[14];
  const float* Wq    = (const float*)d_in[15];
  const float* bq    = (const float*)d_in[16];
  const float* Wk    = (const float*)d_in[17];
  const float* bk    = (const float*)d_in[18];
  const float* Wff   = (const float*)d_in[19];
  const float* bff   = (const float*)d_in[20];
  char* ws = (char*)d_ws;
  float* out = (float*)d_out;

  hipFuncSetAttribute((const void*)dt_decoder,
                      hipFuncAttributeMaxDynamicSharedMemorySize, SM_TOT);

  dt_setup<<<32, 256, 0, stream>>>(embT, Wce, bce, Wq, bq, Wk, bk, Wff, Wre, Wbc, ws);
  dt_encode<<<BB, 256, 0, stream>>>(lemma, Wb4, bb4, Waft, baft, Wall, ball, ws);
  dt_decoder<<<BB/EPB, 1024, SM_TOT, stream>>>(ws, tags, bre, bbc, bff, out);
}

// Round 9
// 504.832 us; speedup vs baseline: 2.1972x; 1.0046x over previous
//
#include <hip/hip_runtime.h>

using fp16 = _Float16;
typedef fp16 f16x4 __attribute__((ext_vector_type(4)));
typedef fp16 f16x8 __attribute__((ext_vector_type(8)));
typedef float f32x4 __attribute__((ext_vector_type(4)));

#define DEVI __device__ __forceinline__

constexpr int LL = 50;
constexpr int BB = 4096;
constexpr int ALPHA = 128;
constexpr int CTX = 20;
constexpr int ATT = 100;
constexpr int EPB = 16;                   // elems per decoder block (fills MFMA M=16)

// ---- fragment image element offsets (fp16 elems) ----
constexpr int FQ_OFF  = 0;       // Wq_eff  [K=160][N=112]  NT=7 KT=5
constexpr int FF_OFF  = 17920;   // Wff_eff [K=224][N=128]  NT=8 KT=7
constexpr int FR_OFF  = 46592;   // Wre     [K=128][N=32]   NT=2 KT=4
constexpr int FB_OFF  = 50688;   // Wbc     [K=32][N=32]    NT=2 KT=1
constexpr int FTQ_OFF = 51712;   // Wq tag rows [64][112]   NT=7 KT=2
constexpr int FTF_OFF = 58880;   // Wff tag rows[64][128]   NT=8 KT=2
constexpr int FRAG_TOT= 67072;

// ---- workspace byte offsets ----
constexpr size_t WS_FRAG = 0;
constexpr size_t WS_PQ   = 134144;                     // f32 [50][112]
constexpr size_t WS_PK   = 156544;                     // f32 [50][112]
constexpr size_t WS_TBL  = 178944;                     // f16: ce|em|wk
constexpr int    TBL_CE  = 0;
constexpr int    TBL_EM  = 2560;
constexpr int    TBL_WK  = 7680;
constexpr int    TBL_N   = 15744;
constexpr size_t WS_K    = 210432;                     // f16 [4096][50][104]
constexpr size_t WS_V    = WS_K + (size_t)BB*5200*2;   // f16 [4096][60][52]

// ---- decoder LDS byte offsets (dynamic shared) ----
constexpr int XQS = 168, XFS = 232, QBS = 104, SCS = 136, TQS = 104, ATS = 56;
constexpr int OFF_XQ = 0;          // f16 [16][168] = 5376
constexpr int OFF_XF = 5376;       // f16 [16][232] = 7424
constexpr int OFF_RP = 12800;      // f16 [16][40]  = 1280
constexpr int OFF_QB = 14080;      // f16 [16][104] = 3328  (tagsl overlay in prologue)
constexpr int OFF_SC = 17408;      // f16 [16][136] = 4352
constexpr int OFF_AT = 21760;      // f16 [16][56]  = 1792
constexpr int OFF_TQ = 23552;      // f16 [16][104] = 3328
constexpr int OFF_TF = 26880;      // f16 [16][128] = 4096
constexpr int OFF_CX = 30976;      // f16 [16][20]  = 640
constexpr int OFF_BB = 31616;      // f32 [40]      = 160
constexpr int OFF_V  = 31776;      // f16 [16][60][52] = 99840
constexpr int OFF_WBC= 131616;     // f16 Wbc frags [2][64][8] = 2048
constexpr int SM_TOT = 133664;     // <= 163840 -> 1 block/CU, 16 waves

DEVI float rcpf(float x) { return __builtin_amdgcn_rcpf(x); }
DEVI float sigm(float x) { return rcpf(1.0f + __expf(-x)); }

DEVI f32x4 mfma16(f16x8 a, f16x8 b, f32x4 c) {
  return __builtin_amdgcn_mfma_f32_16x16x32_f16(a, b, c, 0, 0, 0);
}
DEVI float dot8f(f16x8 a, f16x8 b, float acc) {
  acc = __builtin_amdgcn_fdot2(__builtin_shufflevector(a,a,0,1), __builtin_shufflevector(b,b,0,1), acc, false);
  acc = __builtin_amdgcn_fdot2(__builtin_shufflevector(a,a,2,3), __builtin_shufflevector(b,b,2,3), acc, false);
  acc = __builtin_amdgcn_fdot2(__builtin_shufflevector(a,a,4,5), __builtin_shufflevector(b,b,4,5), acc, false);
  acc = __builtin_amdgcn_fdot2(__builtin_shufflevector(a,a,6,7), __builtin_shufflevector(b,b,6,7), acc, false);
  return acc;
}
DEVI float dot4f(f16x4 a, f16x4 b, float acc) {
  acc = __builtin_amdgcn_fdot2(__builtin_shufflevector(a,a,0,1), __builtin_shufflevector(b,b,0,1), acc, false);
  acc = __builtin_amdgcn_fdot2(__builtin_shufflevector(a,a,2,3), __builtin_shufflevector(b,b,2,3), acc, false);
  return acc;
}

// DPP all-VALU wave64 reductions. REQUIRES v >= 0 (bound_ctrl 0-fill safe).
#define DPP_STEP(OP, CTRL)                                                        \
  { int t_ = __builtin_amdgcn_update_dpp(0, __builtin_bit_cast(int, v), CTRL, 0xF, 0xF, true); \
    v = OP(v, __builtin_bit_cast(float, t_)); }
DEVI float addf(float a, float b) { return a + b; }
DEVI float redmax64(float v) {
  DPP_STEP(fmaxf, 0x111) DPP_STEP(fmaxf, 0x112) DPP_STEP(fmaxf, 0x114)
  DPP_STEP(fmaxf, 0x118) DPP_STEP(fmaxf, 0x142) DPP_STEP(fmaxf, 0x143)
  return __builtin_bit_cast(float, __builtin_amdgcn_readlane(__builtin_bit_cast(int, v), 63));
}
DEVI float redsum64(float v) {
  DPP_STEP(addf, 0x111) DPP_STEP(addf, 0x112) DPP_STEP(addf, 0x114)
  DPP_STEP(addf, 0x118) DPP_STEP(addf, 0x142) DPP_STEP(addf, 0x143)
  return __builtin_bit_cast(float, __builtin_amdgcn_readlane(__builtin_bit_cast(int, v), 63));
}

// LDS-only barrier: all cross-wave deps go through LDS; out-stores are wave-private.
DEVI void lbar() { asm volatile("s_waitcnt lgkmcnt(0)\ns_barrier" ::: "memory"); }

// ================= setup: tables + fragment-packed weights =================
__global__ void dt_setup(const float* __restrict__ embT, const float* __restrict__ Wce,
                         const float* __restrict__ bce,
                         const float* __restrict__ Wq, const float* __restrict__ bq,
                         const float* __restrict__ Wk, const float* __restrict__ bk,
                         const float* __restrict__ Wff, const float* __restrict__ Wre,
                         const float* __restrict__ Wbc, char* __restrict__ ws) {
  __shared__ float ap[LL*60];
  const int tid = threadIdx.x, bid = blockIdx.x;
  if (bid <= 1) {
    for (int i = tid; i < LL*30; i += 256) {
      int p = i / 30, k = i % 30;
      float freq = powf(10000.f, 2.0f*(float)k/60.0f);
      float ang = (float)p / freq;
      ap[p*60 + k]      = sinf(ang);
      ap[p*60 + 30 + k] = cosf(ang);
    }
    __syncthreads();
    const float* W = (bid == 0) ? Wq : Wk;
    const float* bi = (bid == 0) ? bq : bk;
    float* dst = (float*)(ws + (bid == 0 ? WS_PQ : WS_PK));
    for (int i = tid; i < LL*112; i += 256) {
      int r = i / 112, j = i % 112;
      float a = 0.f;
      if (j < ATT) {
        a = bi[j];
        for (int f = 0; f < 60; ++f) a += ap[r*60 + f]*W[f*ATT + j];
      }
      dst[i] = a;
    }
  } else if (bid == 2) {
    fp16* tbl = (fp16*)(ws + WS_TBL);
    for (int i = tid; i < ALPHA*CTX; i += 256) {
      int r = i / CTX, o = i % CTX;
      float a = bce[o];
      for (int e = 0; e < 40; ++e) a += embT[r*40 + e]*Wce[e*CTX + o];
      tbl[TBL_CE + i] = (fp16)a;
    }
    for (int i = tid; i < ALPHA*40; i += 256) tbl[TBL_EM + i] = (fp16)embT[i];
  } else if (bid == 3) {
    fp16* tbl = (fp16*)(ws + WS_TBL);
    for (int i = tid; i < 112*72; i += 256) {
      int a = i / 72, c = i % 72;
      float v = 0.f;
      if (a < ATT) {
        if (c < 20)      v = Wk[(60 + c)*ATT + a];
        else if (c < 60) v = Wk[(80 + (c-20))*ATT + a];
      }
      tbl[TBL_WK + i] = (fp16)v;
    }
  } else {
    fp16* pw = (fp16*)(ws + WS_FRAG);
    for (int gi = (bid-4)*256 + tid; gi < FRAG_TOT; gi += 28*256) {
      int t = gi, img, base, KT;
      if      (t < FF_OFF)  { img = 0; base = t - FQ_OFF;  KT = 5; }
      else if (t < FR_OFF)  { img = 1; base = t - FF_OFF;  KT = 7; }
      else if (t < FB_OFF)  { img = 2; base = t - FR_OFF;  KT = 4; }
      else if (t < FTQ_OFF) { img = 3; base = t - FB_OFF;  KT = 1; }
      else if (t < FTF_OFF) { img = 4; base = t - FTQ_OFF; KT = 2; }
      else                  { img = 5; base = t - FTF_OFF; KT = 2; }
      int j = base & 7, lane = (base >> 3) & 63, frag = base >> 9;
      int nt = frag / KT, kt = frag % KT;
      int k = kt*32 + ((lane >> 4) << 3) + j;
      int n = nt*16 + (lane & 15);
      float v = 0.f;
      if (img == 0) {
        if (n < ATT) {
          if (k < 128)      v = Wq[(80 + k)*ATT + n];
          else if (k < 148) v = Wq[(60 + (k - 128))*ATT + n];
        }
      } else if (img == 1) {
        if (k < 128)      v = Wff[(228 + k)*ALPHA + n];
        else if (k < 188) v = Wff[(k - 128)*ALPHA + n];
        else if (k < 208) v = Wff[(208 + (k - 188))*ALPHA + n];
      } else if (img == 2) {
        if (k < 128 && n < CTX) v = Wre[k*CTX + n];
      } else if (img == 3) {
        if (k < CTX && n < CTX) v = Wbc[k*CTX + n];
      } else if (img == 4) {
        if (n < ATT && k < 64)  v = Wq[(208 + k)*ATT + n];
      } else {
        if (k < 64)             v = Wff[(356 + k)*ALPHA + n];
      }
      pw[gi] = (fp16)v;
    }
  }
}

// ================= encode: ctxt + K + V, one batch elem per block =================
__global__ void dt_encode(const int* __restrict__ lemma,
    const float* __restrict__ Wb4, const float* __restrict__ bb4,
    const float* __restrict__ Waft, const float* __restrict__ baft,
    const float* __restrict__ Wall, const float* __restrict__ ball,
    char* __restrict__ ws) {
  __shared__ fp16 wkl[112*72];
  __shared__ float wb4[800], wa[400], wl[800];
  __shared__ float cel[LL*CTX], b4l[LL*CTX], afl[LL*CTX];
  __shared__ fp16 xin[LL*72];
  __shared__ float bi4[CTX], biA[CTX], biL[CTX];
  __shared__ int lem[52];
  const int b = blockIdx.x, tid = threadIdx.x;
  const fp16* ceg = (const fp16*)(ws + WS_TBL) + TBL_CE;
  const fp16* emg = (const fp16*)(ws + WS_TBL) + TBL_EM;

  { const uint4* s = (const uint4*)((const fp16*)(ws + WS_TBL) + TBL_WK);
    uint4* d = (uint4*)wkl;
    for (int i = tid; i < 112*72*2/16; i += 256) d[i] = s[i]; }
  { const float4* s = (const float4*)Wb4; float4* d = (float4*)wb4;
    for (int i = tid; i < 200; i += 256) d[i] = s[i]; }
  { const float4* s = (const float4*)Waft; float4* d = (float4*)wa;
    for (int i = tid; i < 100; i += 256) d[i] = s[i]; }
  { const float4* s = (const float4*)Wall; float4* d = (float4*)wl;
    for (int i = tid; i < 200; i += 256) d[i] = s[i]; }
  if (tid < CTX) { bi4[tid] = bb4[tid]; biA[tid] = baft[tid]; biL[tid] = ball[tid]; }
  if (tid < LL) lem[tid] = lemma[tid*BB + b];
  __syncthreads();

  for (int i = tid; i < LL*CTX; i += 256)
    cel[i] = (float)ceg[lem[i/CTX]*CTX + (i % CTX)];
  __syncthreads();

  for (int i = tid; i < LL*CTX; i += 256) {
    int l = i / CTX, o = i % CTX;
    float a = bi4[o];
    for (int c = 0; c < CTX; ++c) {
      float c2 = (l >= 2) ? cel[(l-2)*CTX + c] : 0.f;
      float c1 = (l >= 1) ? cel[(l-1)*CTX + c] : 0.f;
      a += c2*wb4[c*CTX + o] + c1*wb4[(CTX+c)*CTX + o];
    }
    b4l[i] = sigm(a);
    float af = biA[o];
    if (l < LL-1)
      for (int c = 0; c < CTX; ++c) af += cel[(l+1)*CTX + c]*wa[c*CTX + o];
    afl[i] = sigm(af);
  }
  __syncthreads();

  for (int i = tid; i < LL*CTX; i += 256) {
    int l = i / CTX, o = i % CTX;
    float a = biL[o];
    for (int c = 0; c < CTX; ++c)
      a += b4l[l*CTX + c]*wl[c*CTX + o] + afl[l*CTX + c]*wl[(CTX+c)*CTX + o];
    xin[l*72 + o] = (fp16)sigm(a);
  }
  for (int i = tid; i < LL*40; i += 256) {
    int l = i / 40, d = i % 40;
    xin[l*72 + 20 + d] = emg[lem[l]*40 + d];
  }
  for (int i = tid; i < LL*12; i += 256) {
    int l = i / 12, c = i % 12;
    xin[l*72 + 60 + c] = (fp16)0.f;
  }
  __syncthreads();

  const float* pkg = (const float*)(ws + WS_PK);
  fp16* Kw = (fp16*)(ws + WS_K) + (size_t)b*5200;
  for (int i = tid; i < 5200; i += 256) {
    int l = i / 104, a = i % 104;
    fp16 v = (fp16)0.f;
    if (a < ATT) {
      float acc = pkg[l*112 + a];
      const fp16* x = xin + l*72;
      const fp16* wv = wkl + a*72;
      #pragma unroll
      for (int k = 0; k < 9; ++k)
        acc = dot8f(*(const f16x8*)(x + 8*k), *(const f16x8*)(wv + 8*k), acc);
      v = (fp16)sigm(acc);
    }
    Kw[i] = v;
  }
  fp16* Vw = (fp16*)(ws + WS_V) + (size_t)b*3120;
  for (int i = tid; i < 3120; i += 256) {
    int d = i / 52, l = i % 52;
    Vw[i] = (l < LL) ? xin[l*72 + d] : (fp16)0.f;
  }
}

// ====== decoder: 16 elems/block, 16 waves, role-split weights ======
// amdgpu_waves_per_eu(4,4): exactly 4 waves/EU = 16 waves/CU -> register
// budget 512/4 = 128/wave (dynamic LDS hides the 1-block/CU limit from the
// compiler, so launch_bounds alone left it targeting 8 waves/EU = 64 regs).
// wave w roles: w<7 Wq-tile | w==7 Wre (Wbc via LDS) | w>=8 Wff-tile.
__global__ __launch_bounds__(1024) __attribute__((amdgpu_waves_per_eu(4, 4)))
void dt_decoder(const char* __restrict__ ws, const float* __restrict__ tags,
                const float* __restrict__ b_re, const float* __restrict__ b_bc,
                const float* __restrict__ bff, float* __restrict__ out) {
  extern __shared__ char sm[];
  fp16* xq   = (fp16*)(sm + OFF_XQ);
  fp16* xf   = (fp16*)(sm + OFF_XF);
  fp16* rp   = (fp16*)(sm + OFF_RP);
  fp16* qb   = (fp16*)(sm + OFF_QB);
  fp16* sc   = (fp16*)(sm + OFF_SC);
  fp16* atb  = (fp16*)(sm + OFF_AT);
  fp16* tagq = (fp16*)(sm + OFF_TQ);
  fp16* tagf = (fp16*)(sm + OFF_TF);
  fp16* ctxs = (fp16*)(sm + OFF_CX);
  float* bbv = (float*)(sm + OFF_BB);
  fp16* Vl   = (fp16*)(sm + OFF_V);
  fp16* wbcl = (fp16*)(sm + OFF_WBC);
  fp16* tagsl = (fp16*)(sm + OFF_QB);   // prologue overlay on qb (2304 <= 3328)

  const int tid = threadIdx.x, lane = tid & 63, w = tid >> 6;
  const int quad = lane >> 4, col = lane & 15;
  const int koff = quad * 8, r0 = quad * 4;
  const int b0 = blockIdx.x * EPB;
  const int b = b0 + w;                 // this wave's batch elem

  // ---- prologue: zero state region [xq..atb] ----
  { uint* z = (uint*)sm;
    for (int j = tid; j < OFF_TQ/4; j += 1024) z[j] = 0; }
  // V stage: 16 elems, coalesced
  { const uint4* s = (const uint4*)(ws + WS_V + (size_t)b0*6240);
    uint4* d = (uint4*)Vl;
    for (int j = tid; j < EPB*390; j += 1024) d[j] = s[j]; }
  if (tid < CTX) { bbv[tid] = b_re[tid]; bbv[20 + tid] = b_bc[tid]; }
  const float bffr = bff[((w & 7) << 4) + col];
  __syncthreads();   // zeros (incl. tagsl overlay region) visible

  // tags into tagsl rows 0..15 (exactly 1024 values)
  { int e = tid >> 6, c = tid & 63;
    tagsl[e*72 + c] = (fp16)tags[(size_t)(b0 + e)*64 + c]; }
  if (tid < EPB) { xq[tid*XQS + 1] = (fp16)1.f; xf[tid*XFS + 1] = (fp16)1.f; }
  if (tid < EPB*CTX) {
    int r = tid / CTX, o = tid % CTX;
    float c1 = sigm(b_bc[o]);
    xq[r*XQS + 128 + o] = (fp16)c1;
    xf[r*XFS + 188 + o] = (fp16)c1;
  }
  for (int j = tid; j < EPB*128; j += 1024) {
    int e = j >> 7, o = j & 127;
    out[(size_t)(b0 + e)*ALPHA + o] = (o == 1) ? 1.f : 0.f;
  }
  __syncthreads();

  // ---- tag projections via MFMA (transient frag regs) ----
  const fp16* fw = (const fp16*)(ws + WS_FRAG);
  {
    f16x8 a0 = *(const f16x8*)(tagsl + (lane & 15)*72 + koff);
    f16x8 a1 = *(const f16x8*)(tagsl + (lane & 15)*72 + 32 + koff);
    if (w < 7) {
      f16x8 t0 = *(const f16x8*)(fw + FTQ_OFF + (((w*2 + 0) << 6) + lane)*8);
      f16x8 t1 = *(const f16x8*)(fw + FTQ_OFF + (((w*2 + 1) << 6) + lane)*8);
      f32x4 c = {0.f,0.f,0.f,0.f};
      c = mfma16(a0, t0, c); c = mfma16(a1, t1, c);
      const int colg = w*16 + col;
      if (colg < 104) {
        #pragma unroll
        for (int r = 0; r < 4; ++r) tagq[(r0 + r)*TQS + colg] = (fp16)c[r];
      }
    } else if (w >= 8) {
      f16x8 u0 = *(const f16x8*)(fw + FTF_OFF + ((((w-8)*2 + 0) << 6) + lane)*8);
      f16x8 u1 = *(const f16x8*)(fw + FTF_OFF + ((((w-8)*2 + 1) << 6) + lane)*8);
      f32x4 d = {0.f,0.f,0.f,0.f};
      d = mfma16(a0, u0, d); d = mfma16(a1, u1, d);
      const int colg = (w-8)*16 + col;
      #pragma unroll
      for (int r = 0; r < 4; ++r) tagf[(r0 + r)*128 + colg] = (fp16)(d[r] + bffr);
    }
  }

  // ---- persistent registers: K row (all waves) + role weights (max 8 frags) ----
  f16x8 KW[13], wW[8];
  { const int lrow = (lane < LL) ? lane : LL-1;
    const fp16* kg = (const fp16*)(ws + WS_K) + (size_t)b*5200 + lrow*104;
    #pragma unroll
    for (int j = 0; j < 13; ++j) KW[j] = *(const f16x8*)(kg + 8*j); }
  if (w < 7) {
    #pragma unroll
    for (int kt = 0; kt < 5; ++kt)
      wW[kt] = *(const f16x8*)(fw + FQ_OFF + (((w*5 + kt) << 6) + lane)*8);
  } else if (w == 7) {
    #pragma unroll
    for (int j = 0; j < 8; ++j)
      wW[j] = *(const f16x8*)(fw + FR_OFF + ((j << 6) + lane)*8);
    // Wbc frags -> LDS (read back per step; wave-private region)
    #pragma unroll
    for (int t = 0; t < 2; ++t) {
      f16x8 v = *(const f16x8*)(fw + FB_OFF + ((t << 6) + lane)*8);
      *(f16x8*)(wbcl + ((t << 6) + lane)*8) = v;
    }
  } else {
    #pragma unroll
    for (int kt = 0; kt < 7; ++kt)
      wW[kt] = *(const f16x8*)(fw + FF_OFF + ((((w-8)*7 + kt) << 6) + lane)*8);
  }

  const float* posqg = (const float*)(ws + WS_PQ);
  const fp16* xq_a = xq + (lane & 15)*XQS + koff;
  const fp16* xf_a = xf + (lane & 15)*XFS + koff;
  const fp16* rp_a = rp + (lane & 15)*40 + koff;

  __syncthreads();

  float pA = 0.f, pB = 0.f;   // previous step's probs (deferred out-store)

  // ==================== recurrence ====================
  for (int i = 1; i < LL; ++i) {
    // ---- Phase A: deferred store + q-GEMM (w<7) / r+ctx-GEMM (w==7) ----
    if (i > 1) {
      size_t ob = ((size_t)(i-1)*BB + b)*ALPHA;
      out[ob + lane] = pA; out[ob + 64 + lane] = pB;
    }
    if (w < 7) {
      const int colg = w*16 + col;
      float pos = posqg[i*112 + colg];
      f32x4 c0 = {0.f,0.f,0.f,0.f}, c1 = {0.f,0.f,0.f,0.f};
      c0 = mfma16(*(const f16x8*)(xq_a + 0*32), wW[0], c0);
      c1 = mfma16(*(const f16x8*)(xq_a + 1*32), wW[1], c1);
      c0 = mfma16(*(const f16x8*)(xq_a + 2*32), wW[2], c0);
      c1 = mfma16(*(const f16x8*)(xq_a + 3*32), wW[3], c1);
      c0 = mfma16(*(const f16x8*)(xq_a + 4*32), wW[4], c0);
      if (colg < 104) {
        #pragma unroll
        for (int r = 0; r < 4; ++r)
          qb[(r0 + r)*QBS + colg] =
            (fp16)sigm(c0[r] + c1[r] + pos + (float)tagq[(r0 + r)*TQS + colg]);
      }
    } else if (w == 7) {
      // r(i-1) = sigm(probs(i-1) @ Wre + bre), 16 elems at once
      f32x4 c0 = {0.f,0.f,0.f,0.f}, c1 = {0.f,0.f,0.f,0.f};
      #pragma unroll
      for (int kt = 0; kt < 4; ++kt) {
        f16x8 a = *(const f16x8*)(xq_a + kt*32);
        c0 = mfma16(a, wW[kt],     c0);
        c1 = mfma16(a, wW[4 + kt], c1);
      }
      const int cA = col, cB = 16 + col;
      #pragma unroll
      for (int r = 0; r < 4; ++r) {
        rp[(r0 + r)*40 + cA] = (fp16)sigm(c0[r] + bbv[cA]);
        if (cB < CTX) rp[(r0 + r)*40 + cB] = (fp16)sigm(c1[r] + bbv[cB]);
      }
      // ctx(i+1) = sigm(r(i-1) @ Wbc + bbc) -> staged (copied in phase D)
      f16x8 ar = *(const f16x8*)rp_a;
      f16x8 wb0 = *(const f16x8*)(wbcl + ((0 << 6) + lane)*8);
      f16x8 wb1 = *(const f16x8*)(wbcl + ((1 << 6) + lane)*8);
      f32x4 d0 = mfma16(ar, wb0, (f32x4){0.f,0.f,0.f,0.f});
      f32x4 d1 = mfma16(ar, wb1, (f32x4){0.f,0.f,0.f,0.f});
      #pragma unroll
      for (int r = 0; r < 4; ++r) {
        ctxs[(r0 + r)*20 + cA] = (fp16)sigm(d0[r] + bbv[20 + cA]);
        if (cB < CTX) ctxs[(r0 + r)*20 + cB] = (fp16)sigm(d1[r] + bbv[20 + cB]);
      }
    }
    lbar();

    // ---- Phase B (all waves, own elem): scores, softmax-50, PV ----
    {
      const fp16* qrow = qb + w*QBS;
      float a0 = 0.f, a1 = 0.f;
      #pragma unroll
      for (int k = 0; k < 12; k += 2) {
        a0 = dot8f(*(const f16x8*)(qrow + 8*k),     KW[k],   a0);
        a1 = dot8f(*(const f16x8*)(qrow + 8*(k+1)), KW[k+1], a1);
      }
      a0 = dot8f(*(const f16x8*)(qrow + 96), KW[12], a0);
      float s = (lane < LL) ? (a0 + a1) : 0.f;     // scores >= 0
      float m  = redmax64(s);
      float e  = (lane < LL) ? __expf(s - m) : 0.f;
      float su = redsum64(e);
      if (lane < LL) atb[w*ATS + lane] = (fp16)(e * rcpf(su));
      const fp16* ar = atb + w*ATS;
      const fp16* vr = Vl + (w*60 + ((lane < 60) ? lane : 59))*52;
      float v0 = 0.f, v1 = 0.f;
      #pragma unroll
      for (int k = 0; k < 12; k += 2) {
        v0 = dot4f(*(const f16x4*)(ar + 4*k),     *(const f16x4*)(vr + 4*k),     v0);
        v1 = dot4f(*(const f16x4*)(ar + 4*(k+1)), *(const f16x4*)(vr + 4*(k+1)), v1);
      }
      v0 = dot4f(*(const f16x4*)(ar + 48), *(const f16x4*)(vr + 48), v0);
      if (lane < 60) xf[w*XFS + 128 + lane] = (fp16)(v0 + v1);
    }
    lbar();

    // ---- Phase C (w>=8): ff-GEMM, 16 elems ----
    if (w >= 8) {
      const int colg = (w-8)*16 + col;
      f32x4 c0 = {0.f,0.f,0.f,0.f}, c1 = {0.f,0.f,0.f,0.f};
      c0 = mfma16(*(const f16x8*)(xf_a + 0*32), wW[0], c0);
      c1 = mfma16(*(const f16x8*)(xf_a + 1*32), wW[1], c1);
      c0 = mfma16(*(const f16x8*)(xf_a + 2*32), wW[2], c0);
      c1 = mfma16(*(const f16x8*)(xf_a + 3*32), wW[3], c1);
      c0 = mfma16(*(const f16x8*)(xf_a + 4*32), wW[4], c0);
      c1 = mfma16(*(const f16x8*)(xf_a + 5*32), wW[5], c1);
      c0 = mfma16(*(const f16x8*)(xf_a + 6*32), wW[6], c0);
      #pragma unroll
      for (int r = 0; r < 4; ++r)
        sc[(r0 + r)*SCS + colg] =
          (fp16)sigm(c0[r] + c1[r] + (float)tagf[(r0 + r)*128 + colg]);
    }
    lbar();

    // ---- Phase D (all waves, own elem): softmax-128; wave 7 also ctx copy ----
    {
      float v0 = (float)sc[w*SCS + lane], v1 = (float)sc[w*SCS + 64 + lane];
      float m = redmax64(fmaxf(v0, v1));
      float e0 = __expf(v0 - m), e1 = __expf(v1 - m);
      float su = redsum64(e0 + e1);
      float inv = rcpf(su);
      pA = e0 * inv; pB = e1 * inv;
      xq[w*XQS + lane] = (fp16)pA; xq[w*XQS + 64 + lane] = (fp16)pB;
      xf[w*XFS + lane] = (fp16)pA; xf[w*XFS + 64 + lane] = (fp16)pB;
    }
    if (w == 7) {
      int r = lane & 15, cg = (lane >> 4) * 5;
      #pragma unroll
      for (int j = 0; j < 5; ++j) {
        fp16 t = ctxs[r*20 + cg + j];
        xq[r*XQS + 128 + cg + j] = t;
        xf[r*XFS + 188 + cg + j] = t;
      }
    }
    lbar();
  }
  { size_t ob = ((size_t)(LL-1)*BB + b)*ALPHA;
    out[ob + lane] = pA; out[ob + 64 + lane] = pB; }
}

extern "C" void kernel_launch(void* const* d_in, const int* in_sizes, int n_in,
                              void* d_out, int out_size, void* d_ws, size_t ws_size,
                              hipStream_t stream) {
  (void)in_sizes; (void)n_in; (void)out_size; (void)ws_size;
  const int*   lemma = (const int*)  d_in[0];
  const float* tags  = (const float*)d_in[1];
  const float* embT  = (const float*)d_in[2];
  const float* Wce   = (const float*)d_in[3];
  const float* bce   = (const float*)d_in[4];
  const float* Wb4   = (const float*)d_in[5];
  const float* bb4   = (const float*)d_in[6];
  const float* Waft  = (const float*)d_in[7];
  const float* baft  = (const float*)d_in[8];
  const float* Wall  = (const float*)d_in[9];
  const float* ball  = (const float*)d_in[10];
  const float* Wre   = (const float*)d_in[11];
  const float* bre   = (const float*)d_in[12];
  const float* Wbc   = (const float*)d_in[13];
  const float* bbc   = (const float*)d_in[14];
  const float* Wq    = (const float*)d_in[15];
  const float* bq    = (const float*)d_in[16];
  const float* Wk    = (const float*)d_in[17];
  const float* bk    = (const float*)d_in[18];
  const float* Wff   = (const float*)d_in[19];
  const float* bff   = (const float*)d_in[20];
  char* ws = (char*)d_ws;
  float* out = (float*)d_out;

  hipFuncSetAttribute((const void*)dt_decoder,
                      hipFuncAttributeMaxDynamicSharedMemorySize, SM_TOT);

  dt_setup<<<32, 256, 0, stream>>>(embT, Wce, bce, Wq, bq, Wk, bk, Wff, Wre, Wbc, ws);
  dt_encode<<<BB, 256, 0, stream>>>(lemma, Wb4, bb4, Waft, baft, Wall, ball, ws);
  dt_decoder<<<BB/EPB, 1024, SM_TOT, stream>>>(ws, tags, bre, bbc, bff, out);
}

// Round 10
// 501.647 us; speedup vs baseline: 2.2111x; 1.0063x over previous
//
#include <hip/hip_runtime.h>

using fp16 = _Float16;
typedef fp16 f16x4 __attribute__((ext_vector_type(4)));
typedef fp16 f16x8 __attribute__((ext_vector_type(8)));
typedef float f32x4 __attribute__((ext_vector_type(4)));

#define DEVI __device__ __forceinline__

constexpr int LL = 50;
constexpr int BB = 4096;
constexpr int ALPHA = 128;
constexpr int CTX = 20;
constexpr int ATT = 100;
constexpr int EPB = 16;                   // 16 elems/block * 256 blocks = 4096: single fill

// ---- fragment image element offsets (fp16 elems) ----
constexpr int FQ_OFF  = 0;       // Wq_eff  [K=160][N=112]  NT=7 KT=5
constexpr int FF_OFF  = 17920;   // Wff_eff [K=224][N=128]  NT=8 KT=7
constexpr int FR_OFF  = 46592;   // Wre     [K=128][N=32]   NT=2 KT=4
constexpr int FB_OFF  = 50688;   // Wbc     [K=32][N=32]    NT=2 KT=1
constexpr int FTQ_OFF = 51712;   // Wq tag rows [64][112]   NT=7 KT=2
constexpr int FTF_OFF = 58880;   // Wff tag rows[64][128]   NT=8 KT=2
constexpr int FRAG_TOT= 67072;

// ---- workspace byte offsets ----
constexpr size_t WS_FRAG = 0;
constexpr size_t WS_PQ   = 134144;                     // f32 [50][112]
constexpr size_t WS_PK   = 156544;                     // f32 [50][112]
constexpr size_t WS_TBL  = 178944;                     // f16: ce|em|wk
constexpr int    TBL_CE  = 0;
constexpr int    TBL_EM  = 2560;
constexpr int    TBL_WK  = 7680;
constexpr int    TBL_N   = 15744;
constexpr size_t WS_K    = 210432;                     // f16 [4096][50][104]
constexpr size_t WS_V    = WS_K + (size_t)BB*5200*2;   // f16 [4096][60][52]

// ---- decoder LDS byte offsets ----
constexpr int XQS = 168, XFS = 232, QBS = 104, SCS = 136, TQS = 104, ATS = 56;
constexpr int OFF_XQ  = 0;          // f16 [16][168] = 5376
constexpr int OFF_XF  = 5376;       // f16 [16][232] = 7424
constexpr int OFF_RP  = 12800;      // f16 [16][40]  = 1280
constexpr int OFF_QB  = 14080;      // f16 [16][104] = 3328 (tagsl overlay in prologue)
constexpr int OFF_SC  = 17408;      // f16 [16][136] = 4352
constexpr int OFF_AT  = 21760;      // f16 [16][56]  = 1792
constexpr int OFF_TQ  = 23552;      // f16 [16][104] = 3328
constexpr int OFF_TF  = 26880;      // f16 [16][128] = 4096
constexpr int OFF_CX  = 30976;      // f16 [16][20]  = 640
constexpr int OFF_BB  = 31616;      // f32 [40]      = 160
constexpr int OFF_SCW = 31776;      // f32 [16][64]  = 4096 (score scratch)
constexpr int OFF_V   = 35872;      // f16 [16][60][52] = 99840
constexpr int SM_TOT  = 135712;     // <= 163840

DEVI float rcpf(float x) { return __builtin_amdgcn_rcpf(x); }
DEVI float sigm(float x) { return rcpf(1.0f + __expf(-x)); }

DEVI f32x4 mfma16(f16x8 a, f16x8 b, f32x4 c) {
  return __builtin_amdgcn_mfma_f32_16x16x32_f16(a, b, c, 0, 0, 0);
}
DEVI float dot8f(f16x8 a, f16x8 b, float acc) {
  acc = __builtin_amdgcn_fdot2(__builtin_shufflevector(a,a,0,1), __builtin_shufflevector(b,b,0,1), acc, false);
  acc = __builtin_amdgcn_fdot2(__builtin_shufflevector(a,a,2,3), __builtin_shufflevector(b,b,2,3), acc, false);
  acc = __builtin_amdgcn_fdot2(__builtin_shufflevector(a,a,4,5), __builtin_shufflevector(b,b,4,5), acc, false);
  acc = __builtin_amdgcn_fdot2(__builtin_shufflevector(a,a,6,7), __builtin_shufflevector(b,b,6,7), acc, false);
  return acc;
}
DEVI float dot4f(f16x4 a, f16x4 b, float acc) {
  acc = __builtin_amdgcn_fdot2(__builtin_shufflevector(a,a,0,1), __builtin_shufflevector(b,b,0,1), acc, false);
  acc = __builtin_amdgcn_fdot2(__builtin_shufflevector(a,a,2,3), __builtin_shufflevector(b,b,2,3), acc, false);
  return acc;
}

// DPP all-VALU wave64 reductions. REQUIRES v >= 0 (bound_ctrl 0-fill safe).
#define DPP_STEP(OP, CTRL)                                                        \
  { int t_ = __builtin_amdgcn_update_dpp(0, __builtin_bit_cast(int, v), CTRL, 0xF, 0xF, true); \
    v = OP(v, __builtin_bit_cast(float, t_)); }
DEVI float addf(float a, float b) { return a + b; }
DEVI float redmax64(float v) {
  DPP_STEP(fmaxf, 0x111) DPP_STEP(fmaxf, 0x112) DPP_STEP(fmaxf, 0x114)
  DPP_STEP(fmaxf, 0x118) DPP_STEP(fmaxf, 0x142) DPP_STEP(fmaxf, 0x143)
  return __builtin_bit_cast(float, __builtin_amdgcn_readlane(__builtin_bit_cast(int, v), 63));
}
DEVI float redsum64(float v) {
  DPP_STEP(addf, 0x111) DPP_STEP(addf, 0x112) DPP_STEP(addf, 0x114)
  DPP_STEP(addf, 0x118) DPP_STEP(addf, 0x142) DPP_STEP(addf, 0x143)
  return __builtin_bit_cast(float, __builtin_amdgcn_readlane(__builtin_bit_cast(int, v), 63));
}

// LDS-only barrier; memory clobber also pins the per-step weight loads in-loop.
DEVI void lbar() { asm volatile("s_waitcnt lgkmcnt(0)\ns_barrier" ::: "memory"); }

// ================= setup: tables + fragment-packed weights =================
__global__ void dt_setup(const float* __restrict__ embT, const float* __restrict__ Wce,
                         const float* __restrict__ bce,
                         const float* __restrict__ Wq, const float* __restrict__ bq,
                         const float* __restrict__ Wk, const float* __restrict__ bk,
                         const float* __restrict__ Wff, const float* __restrict__ Wre,
                         const float* __restrict__ Wbc, char* __restrict__ ws) {
  __shared__ float ap[LL*60];
  const int tid = threadIdx.x, bid = blockIdx.x;
  if (bid <= 1) {
    for (int i = tid; i < LL*30; i += 256) {
      int p = i / 30, k = i % 30;
      float freq = powf(10000.f, 2.0f*(float)k/60.0f);
      float ang = (float)p / freq;
      ap[p*60 + k]      = sinf(ang);
      ap[p*60 + 30 + k] = cosf(ang);
    }
    __syncthreads();
    const float* W = (bid == 0) ? Wq : Wk;
    const float* bi = (bid == 0) ? bq : bk;
    float* dst = (float*)(ws + (bid == 0 ? WS_PQ : WS_PK));
    for (int i = tid; i < LL*112; i += 256) {
      int r = i / 112, j = i % 112;
      float a = 0.f;
      if (j < ATT) {
        a = bi[j];
        for (int f = 0; f < 60; ++f) a += ap[r*60 + f]*W[f*ATT + j];
      }
      dst[i] = a;
    }
  } else if (bid == 2) {
    fp16* tbl = (fp16*)(ws + WS_TBL);
    for (int i = tid; i < ALPHA*CTX; i += 256) {
      int r = i / CTX, o = i % CTX;
      float a = bce[o];
      for (int e = 0; e < 40; ++e) a += embT[r*40 + e]*Wce[e*CTX + o];
      tbl[TBL_CE + i] = (fp16)a;
    }
    for (int i = tid; i < ALPHA*40; i += 256) tbl[TBL_EM + i] = (fp16)embT[i];
  } else if (bid == 3) {
    fp16* tbl = (fp16*)(ws + WS_TBL);
    for (int i = tid; i < 112*72; i += 256) {
      int a = i / 72, c = i % 72;
      float v = 0.f;
      if (a < ATT) {
        if (c < 20)      v = Wk[(60 + c)*ATT + a];
        else if (c < 60) v = Wk[(80 + (c-20))*ATT + a];
      }
      tbl[TBL_WK + i] = (fp16)v;
    }
  } else {
    fp16* pw = (fp16*)(ws + WS_FRAG);
    for (int gi = (bid-4)*256 + tid; gi < FRAG_TOT; gi += 28*256) {
      int t = gi, img, base, KT;
      if      (t < FF_OFF)  { img = 0; base = t - FQ_OFF;  KT = 5; }
      else if (t < FR_OFF)  { img = 1; base = t - FF_OFF;  KT = 7; }
      else if (t < FB_OFF)  { img = 2; base = t - FR_OFF;  KT = 4; }
      else if (t < FTQ_OFF) { img = 3; base = t - FB_OFF;  KT = 1; }
      else if (t < FTF_OFF) { img = 4; base = t - FTQ_OFF; KT = 2; }
      else                  { img = 5; base = t - FTF_OFF; KT = 2; }
      int j = base & 7, lane = (base >> 3) & 63, frag = base >> 9;
      int nt = frag / KT, kt = frag % KT;
      int k = kt*32 + ((lane >> 4) << 3) + j;
      int n = nt*16 + (lane & 15);
      float v = 0.f;
      if (img == 0) {
        if (n < ATT) {
          if (k < 128)      v = Wq[(80 + k)*ATT + n];
          else if (k < 148) v = Wq[(60 + (k - 128))*ATT + n];
        }
      } else if (img == 1) {
        if (k < 128)      v = Wff[(228 + k)*ALPHA + n];
        else if (k < 188) v = Wff[(k - 128)*ALPHA + n];
        else if (k < 208) v = Wff[(208 + (k - 188))*ALPHA + n];
      } else if (img == 2) {
        if (k < 128 && n < CTX) v = Wre[k*CTX + n];
      } else if (img == 3) {
        if (k < CTX && n < CTX) v = Wbc[k*CTX + n];
      } else if (img == 4) {
        if (n < ATT && k < 64)  v = Wq[(208 + k)*ATT + n];
      } else {
        if (k < 64)             v = Wff[(356 + k)*ALPHA + n];
      }
      pw[gi] = (fp16)v;
    }
  }
}

// ================= encode: ctxt + K + V, one batch elem per block =================
__global__ void dt_encode(const int* __restrict__ lemma,
    const float* __restrict__ Wb4, const float* __restrict__ bb4,
    const float* __restrict__ Waft, const float* __restrict__ baft,
    const float* __restrict__ Wall, const float* __restrict__ ball,
    char* __restrict__ ws) {
  __shared__ fp16 wkl[112*72];
  __shared__ float wb4[800], wa[400], wl[800];
  __shared__ float cel[LL*CTX], b4l[LL*CTX], afl[LL*CTX];
  __shared__ fp16 xin[LL*72];
  __shared__ float bi4[CTX], biA[CTX], biL[CTX];
  __shared__ int lem[52];
  const int b = blockIdx.x, tid = threadIdx.x;
  const fp16* ceg = (const fp16*)(ws + WS_TBL) + TBL_CE;
  const fp16* emg = (const fp16*)(ws + WS_TBL) + TBL_EM;

  { const uint4* s = (const uint4*)((const fp16*)(ws + WS_TBL) + TBL_WK);
    uint4* d = (uint4*)wkl;
    for (int i = tid; i < 112*72*2/16; i += 256) d[i] = s[i]; }
  { const float4* s = (const float4*)Wb4; float4* d = (float4*)wb4;
    for (int i = tid; i < 200; i += 256) d[i] = s[i]; }
  { const float4* s = (const float4*)Waft; float4* d = (float4*)wa;
    for (int i = tid; i < 100; i += 256) d[i] = s[i]; }
  { const float4* s = (const float4*)Wall; float4* d = (float4*)wl;
    for (int i = tid; i < 200; i += 256) d[i] = s[i]; }
  if (tid < CTX) { bi4[tid] = bb4[tid]; biA[tid] = baft[tid]; biL[tid] = ball[tid]; }
  if (tid < LL) lem[tid] = lemma[tid*BB + b];
  __syncthreads();

  for (int i = tid; i < LL*CTX; i += 256)
    cel[i] = (float)ceg[lem[i/CTX]*CTX + (i % CTX)];
  __syncthreads();

  for (int i = tid; i < LL*CTX; i += 256) {
    int l = i / CTX, o = i % CTX;
    float a = bi4[o];
    for (int c = 0; c < CTX; ++c) {
      float c2 = (l >= 2) ? cel[(l-2)*CTX + c] : 0.f;
      float c1 = (l >= 1) ? cel[(l-1)*CTX + c] : 0.f;
      a += c2*wb4[c*CTX + o] + c1*wb4[(CTX+c)*CTX + o];
    }
    b4l[i] = sigm(a);
    float af = biA[o];
    if (l < LL-1)
      for (int c = 0; c < CTX; ++c) af += cel[(l+1)*CTX + c]*wa[c*CTX + o];
    afl[i] = sigm(af);
  }
  __syncthreads();

  for (int i = tid; i < LL*CTX; i += 256) {
    int l = i / CTX, o = i % CTX;
    float a = biL[o];
    for (int c = 0; c < CTX; ++c)
      a += b4l[l*CTX + c]*wl[c*CTX + o] + afl[l*CTX + c]*wl[(CTX+c)*CTX + o];
    xin[l*72 + o] = (fp16)sigm(a);
  }
  for (int i = tid; i < LL*40; i += 256) {
    int l = i / 40, d = i % 40;
    xin[l*72 + 20 + d] = emg[lem[l]*40 + d];
  }
  for (int i = tid; i < LL*12; i += 256) {
    int l = i / 12, c = i % 12;
    xin[l*72 + 60 + c] = (fp16)0.f;
  }
  __syncthreads();

  const float* pkg = (const float*)(ws + WS_PK);
  fp16* Kw = (fp16*)(ws + WS_K) + (size_t)b*5200;
  for (int i = tid; i < 5200; i += 256) {
    int l = i / 104, a = i % 104;
    fp16 v = (fp16)0.f;
    if (a < ATT) {
      float acc = pkg[l*112 + a];
      const fp16* x = xin + l*72;
      const fp16* wv = wkl + a*72;
      #pragma unroll
      for (int k = 0; k < 9; ++k)
        acc = dot8f(*(const f16x8*)(x + 8*k), *(const f16x8*)(wv + 8*k), acc);
      v = (fp16)sigm(acc);
    }
    Kw[i] = v;
  }
  fp16* Vw = (fp16*)(ws + WS_V) + (size_t)b*3120;
  for (int i = tid; i < 3120; i += 256) {
    int d = i / 52, l = i % 52;
    Vw[i] = (l < LL) ? xin[l*72 + d] : (fp16)0.f;
  }
}

// ====== decoder: 16 waves/16 elems, single fill (256 blocks) ======
// Register plan for the 64-arch budget (1024-thread default):
//   - K lives as 12 MFMA B-fragments (48 regs, MFMA-only -> AGPR file)
//   - role weights (Wq/Wff/Wre/Wbc) streamed from global EVERY step (L2/L3-hot,
//     transient VGPRs; lbar()'s memory clobber blocks LICM re-hoisting)
//   - V + all state in LDS; scores via MFMA, PV + softmaxes on VALU
__global__ __launch_bounds__(1024)
void dt_decoder(const char* __restrict__ ws, const float* __restrict__ tags,
                const float* __restrict__ b_re, const float* __restrict__ b_bc,
                const float* __restrict__ bff, float* __restrict__ out) {
  extern __shared__ char sm[];
  fp16* xq   = (fp16*)(sm + OFF_XQ);
  fp16* xf   = (fp16*)(sm + OFF_XF);
  fp16* rp   = (fp16*)(sm + OFF_RP);
  fp16* qb   = (fp16*)(sm + OFF_QB);
  fp16* sc   = (fp16*)(sm + OFF_SC);
  fp16* atb  = (fp16*)(sm + OFF_AT);
  fp16* tagq = (fp16*)(sm + OFF_TQ);
  fp16* tagf = (fp16*)(sm + OFF_TF);
  fp16* ctxs = (fp16*)(sm + OFF_CX);
  float* bbv = (float*)(sm + OFF_BB);
  float* scw = (float*)(sm + OFF_SCW);
  fp16* Vl   = (fp16*)(sm + OFF_V);
  fp16* tagsl = (fp16*)(sm + OFF_QB);   // prologue overlay on qb (2304 <= 3328)

  const int tid = threadIdx.x, lane = tid & 63, w = tid >> 6;
  const int quad = lane >> 4, col = lane & 15;
  const int koff = quad * 8, r0 = quad * 4;
  const int b0 = blockIdx.x * EPB;
  const int b = b0 + w;                 // this wave's batch elem

  // ---- prologue: zero state region [xq..atb] ----
  { uint* z = (uint*)sm;
    for (int j = tid; j < OFF_TQ/4; j += 1024) z[j] = 0; }
  // V stage: 16 elems, coalesced (99840 B)
  { const uint4* s = (const uint4*)(ws + WS_V + (size_t)b0*6240);
    uint4* d = (uint4*)Vl;
    for (int j = tid; j < EPB*390; j += 1024) d[j] = s[j]; }
  if (tid < CTX) { bbv[tid] = b_re[tid]; bbv[20 + tid] = b_bc[tid]; }
  __syncthreads();   // zeros (incl. tagsl overlay region) visible

  // tags into tagsl rows 0..15 (exactly 1024 values)
  { int e = tid >> 6, c = tid & 63;
    tagsl[e*72 + c] = (fp16)tags[(size_t)(b0 + e)*64 + c]; }
  if (tid < EPB) { xq[tid*XQS + 1] = (fp16)1.f; xf[tid*XFS + 1] = (fp16)1.f; }
  if (tid < EPB*CTX) {
    int r = tid / CTX, o = tid % CTX;
    float c1 = sigm(b_bc[o]);
    xq[r*XQS + 128 + o] = (fp16)c1;
    xf[r*XFS + 188 + o] = (fp16)c1;
  }
  for (int j = tid; j < EPB*128; j += 1024) {
    int e = j >> 7, o = j & 127;
    out[(size_t)(b0 + e)*ALPHA + o] = (o == 1) ? 1.f : 0.f;
  }
  __syncthreads();

  // ---- tag projections via MFMA (transient frag regs, weights from global) ----
  const fp16* fw = (const fp16*)(ws + WS_FRAG);
  {
    f16x8 a0 = *(const f16x8*)(tagsl + col*72 + koff);
    f16x8 a1 = *(const f16x8*)(tagsl + col*72 + 32 + koff);
    if (w < 7) {
      f16x8 t0 = *(const f16x8*)(fw + FTQ_OFF + (((w*2 + 0) << 6) + lane)*8);
      f16x8 t1 = *(const f16x8*)(fw + FTQ_OFF + (((w*2 + 1) << 6) + lane)*8);
      f32x4 c = {0.f,0.f,0.f,0.f};
      c = mfma16(a0, t0, c); c = mfma16(a1, t1, c);
      const int colg = w*16 + col;
      if (colg < 104) {
        #pragma unroll
        for (int r = 0; r < 4; ++r) tagq[(r0 + r)*TQS + colg] = (fp16)c[r];
      }
    } else if (w >= 8) {
      const float bffr = bff[(w-8)*16 + col];
      f16x8 u0 = *(const f16x8*)(fw + FTF_OFF + ((((w-8)*2 + 0) << 6) + lane)*8);
      f16x8 u1 = *(const f16x8*)(fw + FTF_OFF + ((((w-8)*2 + 1) << 6) + lane)*8);
      f32x4 d = {0.f,0.f,0.f,0.f};
      d = mfma16(a0, u0, d); d = mfma16(a1, u1, d);
      const int colg = (w-8)*16 + col;
      #pragma unroll
      for (int r = 0; r < 4; ++r) tagf[(r0 + r)*128 + colg] = (fp16)(d[r] + bffr);
    }
  }

  // ---- persistent: K as 12 MFMA B-fragments (AGPR-friendly) + f16x4 tail ----
  // B-frag layout (16x16x32): lane holds B[k=c*32+quad*8+j][n=t*16+col];
  // B[k][n] = K[pos=n][dim=k]  (scores D = q . K^T).
  f16x8 KF[12];
  f16x4 ktail;
  { const fp16* kg = (const fp16*)(ws + WS_K) + (size_t)b*5200;
    #pragma unroll
    for (int c = 0; c < 3; ++c) {
      #pragma unroll
      for (int t = 0; t < 4; ++t) {
        int pos = t*16 + col; if (pos >= LL) pos = LL-1;   // clamped rows masked later
        KF[c*4 + t] = *(const f16x8*)(kg + pos*104 + c*32 + koff);
      }
    }
    int pl = (lane < LL) ? lane : LL-1;
    ktail = *(const f16x4*)(kg + pl*104 + 96);             // dims 96..99, row=lane
  }

  const float* posqg = (const float*)(ws + WS_PQ);
  const fp16* xq_a = xq + col*XQS + koff;
  const fp16* xf_a = xf + col*XFS + koff;
  const fp16* rp_a = rp + col*40 + koff;

  __syncthreads();

  float pA = 0.f, pB = 0.f;   // previous step's probs (deferred out-store)

  // ==================== recurrence ====================
  for (int i = 1; i < LL; ++i) {
    // ---- Phase A: deferred store + q-GEMM (w<7) / re+bc (w==7); weights streamed ----
    if (i > 1) {
      size_t ob = ((size_t)(i-1)*BB + b)*ALPHA;
      out[ob + lane] = pA; out[ob + 64 + lane] = pB;
    }
    if (w < 7) {
      const int colg = w*16 + col;
      float pos = posqg[i*112 + colg];
      f16x8 q0 = *(const f16x8*)(fw + FQ_OFF + (((w*5 + 0) << 6) + lane)*8);
      f16x8 q1 = *(const f16x8*)(fw + FQ_OFF + (((w*5 + 1) << 6) + lane)*8);
      f16x8 q2 = *(const f16x8*)(fw + FQ_OFF + (((w*5 + 2) << 6) + lane)*8);
      f16x8 q3 = *(const f16x8*)(fw + FQ_OFF + (((w*5 + 3) << 6) + lane)*8);
      f16x8 q4 = *(const f16x8*)(fw + FQ_OFF + (((w*5 + 4) << 6) + lane)*8);
      f32x4 c0 = {0.f,0.f,0.f,0.f}, c1 = {0.f,0.f,0.f,0.f};
      c0 = mfma16(*(const f16x8*)(xq_a + 0*32), q0, c0);
      c1 = mfma16(*(const f16x8*)(xq_a + 1*32), q1, c1);
      c0 = mfma16(*(const f16x8*)(xq_a + 2*32), q2, c0);
      c1 = mfma16(*(const f16x8*)(xq_a + 3*32), q3, c1);
      c0 = mfma16(*(const f16x8*)(xq_a + 4*32), q4, c0);
      if (colg < 104) {
        #pragma unroll
        for (int r = 0; r < 4; ++r)
          qb[(r0 + r)*QBS + colg] =
            (fp16)sigm(c0[r] + c1[r] + pos + (float)tagq[(r0 + r)*TQS + colg]);
      }
    } else if (w == 7) {
      // r(i-1) = sigm(probs(i-1) @ Wre + bre)
      f32x4 c0 = {0.f,0.f,0.f,0.f}, c1 = {0.f,0.f,0.f,0.f};
      #pragma unroll
      for (int kt = 0; kt < 4; ++kt) {
        f16x8 w0 = *(const f16x8*)(fw + FR_OFF + (((0*4 + kt) << 6) + lane)*8);
        f16x8 w1 = *(const f16x8*)(fw + FR_OFF + (((1*4 + kt) << 6) + lane)*8);
        f16x8 a = *(const f16x8*)(xq_a + kt*32);
        c0 = mfma16(a, w0, c0);
        c1 = mfma16(a, w1, c1);
      }
      const int cA = col, cB = 16 + col;
      #pragma unroll
      for (int r = 0; r < 4; ++r) {
        rp[(r0 + r)*40 + cA] = (fp16)sigm(c0[r] + bbv[cA]);
        if (cB < CTX) rp[(r0 + r)*40 + cB] = (fp16)sigm(c1[r] + bbv[cB]);
      }
      // ctx(i+1) = sigm(r(i-1) @ Wbc + bbc) -> staged (copied in phase D)
      f16x8 wb0 = *(const f16x8*)(fw + FB_OFF + ((0 << 6) + lane)*8);
      f16x8 wb1 = *(const f16x8*)(fw + FB_OFF + ((1 << 6) + lane)*8);
      f16x8 ar = *(const f16x8*)rp_a;
      f32x4 d0 = mfma16(ar, wb0, (f32x4){0.f,0.f,0.f,0.f});
      f32x4 d1 = mfma16(ar, wb1, (f32x4){0.f,0.f,0.f,0.f});
      #pragma unroll
      for (int r = 0; r < 4; ++r) {
        ctxs[(r0 + r)*20 + cA] = (fp16)sigm(d0[r] + bbv[20 + cA]);
        if (cB < CTX) ctxs[(r0 + r)*20 + cB] = (fp16)sigm(d1[r] + bbv[20 + cB]);
      }
    }
    lbar();

    // ---- Phase B (all waves, own elem): MFMA scores, softmax-50, VALU PV ----
    {
      // scores D[e][pos]: A = all elems' q (LDS), B = this elem's K frags (regs)
      f32x4 s0 = {0.f,0.f,0.f,0.f}, s1 = {0.f,0.f,0.f,0.f};
      f32x4 s2 = {0.f,0.f,0.f,0.f}, s3 = {0.f,0.f,0.f,0.f};
      #pragma unroll
      for (int c = 0; c < 3; ++c) {
        f16x8 a = *(const f16x8*)(qb + col*QBS + c*32 + koff);
        s0 = mfma16(a, KF[c*4 + 0], s0);
        s1 = mfma16(a, KF[c*4 + 1], s1);
        s2 = mfma16(a, KF[c*4 + 2], s2);
        s3 = mfma16(a, KF[c*4 + 3], s3);
      }
      // extract row w (held by lane group w>>2, reg w&3) into score scratch
      if (quad == (w >> 2)) {
        const int sel = w & 3;
        float* sw = scw + w*64;
        sw[ 0 + col] = sel==0 ? s0[0] : sel==1 ? s0[1] : sel==2 ? s0[2] : s0[3];
        sw[16 + col] = sel==0 ? s1[0] : sel==1 ? s1[1] : sel==2 ? s1[2] : s1[3];
        sw[32 + col] = sel==0 ? s2[0] : sel==1 ? s2[1] : sel==2 ? s2[2] : s2[3];
        sw[48 + col] = sel==0 ? s3[0] : sel==1 ? s3[1] : sel==2 ? s3[2] : s3[3];
      }
      // tail dims 96..99 on VALU (per-position lane)
      f16x4 qt = *(const f16x4*)(qb + w*QBS + 96);
      float s = scw[w*64 + lane] + dot4f(qt, ktail, 0.f);
      s = (lane < LL) ? s : 0.f;                    // scores >= 0
      float m  = redmax64(s);
      float e  = (lane < LL) ? __expf(s - m) : 0.f;
      float su = redsum64(e);
      if (lane < LL) atb[w*ATS + lane] = (fp16)(e * rcpf(su));
      // PV: lane d reads V row d from LDS
      const fp16* ar = atb + w*ATS;
      const fp16* vr = Vl + (w*60 + ((lane < 60) ? lane : 59))*52;
      float v0 = 0.f, v1 = 0.f;
      #pragma unroll
      for (int k = 0; k < 12; k += 2) {
        v0 = dot4f(*(const f16x4*)(ar + 4*k),     *(const f16x4*)(vr + 4*k),     v0);
        v1 = dot4f(*(const f16x4*)(ar + 4*(k+1)), *(const f16x4*)(vr + 4*(k+1)), v1);
      }
      v0 = dot4f(*(const f16x4*)(ar + 48), *(const f16x4*)(vr + 48), v0);
      if (lane < 60) xf[w*XFS + 128 + lane] = (fp16)(v0 + v1);
    }
    lbar();

    // ---- Phase C (w>=8): ff-GEMM, weights streamed ----
    if (w >= 8) {
      const int colg = (w-8)*16 + col;
      f16x8 f0 = *(const f16x8*)(fw + FF_OFF + ((((w-8)*7 + 0) << 6) + lane)*8);
      f16x8 f1 = *(const f16x8*)(fw + FF_OFF + ((((w-8)*7 + 1) << 6) + lane)*8);
      f16x8 f2 = *(const f16x8*)(fw + FF_OFF + ((((w-8)*7 + 2) << 6) + lane)*8);
      f16x8 f3 = *(const f16x8*)(fw + FF_OFF + ((((w-8)*7 + 3) << 6) + lane)*8);
      f16x8 f4 = *(const f16x8*)(fw + FF_OFF + ((((w-8)*7 + 4) << 6) + lane)*8);
      f16x8 f5 = *(const f16x8*)(fw + FF_OFF + ((((w-8)*7 + 5) << 6) + lane)*8);
      f16x8 f6 = *(const f16x8*)(fw + FF_OFF + ((((w-8)*7 + 6) << 6) + lane)*8);
      f32x4 c0 = {0.f,0.f,0.f,0.f}, c1 = {0.f,0.f,0.f,0.f};
      c0 = mfma16(*(const f16x8*)(xf_a + 0*32), f0, c0);
      c1 = mfma16(*(const f16x8*)(xf_a + 1*32), f1, c1);
      c0 = mfma16(*(const f16x8*)(xf_a + 2*32), f2, c0);
      c1 = mfma16(*(const f16x8*)(xf_a + 3*32), f3, c1);
      c0 = mfma16(*(const f16x8*)(xf_a + 4*32), f4, c0);
      c1 = mfma16(*(const f16x8*)(xf_a + 5*32), f5, c1);
      c0 = mfma16(*(const f16x8*)(xf_a + 6*32), f6, c0);
      #pragma unroll
      for (int r = 0; r < 4; ++r)
        sc[(r0 + r)*SCS + colg] =
          (fp16)sigm(c0[r] + c1[r] + (float)tagf[(r0 + r)*128 + colg]);
    }
    lbar();

    // ---- Phase D (all waves, own elem): softmax-128; wave 7 also ctx copy ----
    {
      float v0 = (float)sc[w*SCS + lane], v1 = (float)sc[w*SCS + 64 + lane];
      float m = redmax64(fmaxf(v0, v1));
      float e0 = __expf(v0 - m), e1 = __expf(v1 - m);
      float su = redsum64(e0 + e1);
      float inv = rcpf(su);
      pA = e0 * inv; pB = e1 * inv;
      xq[w*XQS + lane] = (fp16)pA; xq[w*XQS + 64 + lane] = (fp16)pB;
      xf[w*XFS + lane] = (fp16)pA; xf[w*XFS + 64 + lane] = (fp16)pB;
    }
    if (w == 7) {
      int r = lane & 15, cg = (lane >> 4) * 5;
      #pragma unroll
      for (int j = 0; j < 5; ++j) {
        fp16 t = ctxs[r*20 + cg + j];
        xq[r*XQS + 128 + cg + j] = t;
        xf[r*XFS + 188 + cg + j] = t;
      }
    }
    lbar();
  }
  { size_t ob = ((size_t)(LL-1)*BB + b)*ALPHA;
    out[ob + lane] = pA; out[ob + 64 + lane] = pB; }
}

extern "C" void kernel_launch(void* const* d_in, const int* in_sizes, int n_in,
                              void* d_out, int out_size, void* d_ws, size_t ws_size,
                              hipStream_t stream) {
  (void)in_sizes; (void)n_in; (void)out_size; (void)ws_size;
  const int*   lemma = (const int*)  d_in[0];
  const float* tags  = (const float*)d_in[1];
  const float* embT  = (const float*)d_in[2];
  const float* Wce   = (const float*)d_in[3];
  const float* bce   = (const float*)d_in[4];
  const float* Wb4   = (const float*)d_in[5];
  const float* bb4   = (const float*)d_in[6];
  const float* Waft  = (const float*)d_in[7];
  const float* baft  = (const float*)d_in[8];
  const float* Wall  = (const float*)d_in[9];
  const float* ball  = (const float*)d_in[10];
  const float* Wre   = (const float*)d_in[11];
  const float* bre   = (const float*)d_in[12];
  const float* Wbc   = (const float*)d_in[13];
  const float* bbc   = (const float*)d_in[14];
  const float* Wq    = (const float*)d_in[15];
  const float* bq    = (const float*)d_in[16];
  const float* Wk    = (const float*)d_in[17];
  const float* bk    = (const float*)d_in[18];
  const float* Wff   = (const float*)d_in[19];
  const float* bff   = (const float*)d_in[20];
  char* ws = (char*)d_ws;
  float* out = (float*)d_out;

  hipFuncSetAttribute((const void*)dt_decoder,
                      hipFuncAttributeMaxDynamicSharedMemorySize, SM_TOT);

  dt_setup<<<32, 256, 0, stream>>>(embT, Wce, bce, Wq, bq, Wk, bk, Wff, Wre, Wbc, ws);
  dt_encode<<<BB, 256, 0, stream>>>(lemma, Wb4, bb4, Waft, baft, Wall, ball, ws);
  dt_decoder<<<BB/EPB, 1024, SM_TOT, stream>>>(ws, tags, bre, bbc, bff, out);
}

// Round 11
// 496.672 us; speedup vs baseline: 2.2333x; 1.0100x over previous
//
#include <hip/hip_runtime.h>

using fp16 = _Float16;
typedef fp16 f16x4 __attribute__((ext_vector_type(4)));
typedef fp16 f16x8 __attribute__((ext_vector_type(8)));
typedef float f32x4 __attribute__((ext_vector_type(4)));

#define DEVI __device__ __forceinline__

constexpr int LL = 50;
constexpr int BB = 4096;
constexpr int ALPHA = 128;
constexpr int CTX = 20;
constexpr int ATT = 100;
constexpr int EPB = 16;                   // 16 elems/block * 256 blocks = 4096: single fill

// ---- fragment image element offsets (fp16 elems) ----
constexpr int FQ_OFF  = 0;       // Wq_eff  [K=160][N=112]  NT=7 KT=5
constexpr int FF_OFF  = 17920;   // Wff_eff [K=224][N=128]  NT=8 KT=7
constexpr int FR_OFF  = 46592;   // Wre     [K=128][N=32]   NT=2 KT=4
constexpr int FB_OFF  = 50688;   // Wbc     [K=32][N=32]    NT=2 KT=1
constexpr int FTQ_OFF = 51712;   // Wq tag rows [64][112]   NT=7 KT=2
constexpr int FTF_OFF = 58880;   // Wff tag rows[64][128]   NT=8 KT=2
constexpr int FRAG_TOT= 67072;

// ---- workspace byte offsets ----
constexpr size_t WS_FRAG = 0;
constexpr size_t WS_PQ   = 134144;                     // f32 [50][112]
constexpr size_t WS_PK   = 156544;                     // f32 [50][112]
constexpr size_t WS_TBL  = 178944;                     // f16: ce|em|wk
constexpr int    TBL_CE  = 0;
constexpr int    TBL_EM  = 2560;
constexpr int    TBL_WK  = 7680;
constexpr int    TBL_N   = 15744;
constexpr size_t WS_K    = 210432;                     // f16 [4096][50][104]
constexpr size_t WS_V    = WS_K + (size_t)BB*5200*2;   // f16 [4096][60][52]

// ---- decoder LDS byte offsets ----
constexpr int XQS = 168, XFS = 232, QBS = 104, SCS = 136, TQS = 104, ATS = 56;
constexpr int OFF_XQ  = 0;          // f16 [16][168] = 5376
constexpr int OFF_XF  = 5376;       // f16 [16][232] = 7424
constexpr int OFF_RP  = 12800;      // f16 [16][40]  = 1280
constexpr int OFF_QB  = 14080;      // f16 [16][104] = 3328 (tagsl overlay in prologue)
constexpr int OFF_SC  = 17408;      // f16 [16][136] = 4352
constexpr int OFF_AT  = 21760;      // f16 [16][56]  = 1792
constexpr int OFF_TQ  = 23552;      // f16 [16][104] = 3328
constexpr int OFF_TF  = 26880;      // f16 [16][128] = 4096
constexpr int OFF_CX  = 30976;      // f16 [16][20]  = 640
constexpr int OFF_BB  = 31616;      // f32 [40]      = 160
constexpr int OFF_SCW = 31776;      // f32 [16][64]  = 4096 (score scratch)
constexpr int OFF_V   = 35872;      // f16 [16][60][52] = 99840
constexpr int SM_TOT  = 135712;     // <= 163840

DEVI float rcpf(float x) { return __builtin_amdgcn_rcpf(x); }
DEVI float sigm(float x) { return rcpf(1.0f + __expf(-x)); }

DEVI f32x4 mfma16(f16x8 a, f16x8 b, f32x4 c) {
  return __builtin_amdgcn_mfma_f32_16x16x32_f16(a, b, c, 0, 0, 0);
}
DEVI float dot8f(f16x8 a, f16x8 b, float acc) {
  acc = __builtin_amdgcn_fdot2(__builtin_shufflevector(a,a,0,1), __builtin_shufflevector(b,b,0,1), acc, false);
  acc = __builtin_amdgcn_fdot2(__builtin_shufflevector(a,a,2,3), __builtin_shufflevector(b,b,2,3), acc, false);
  acc = __builtin_amdgcn_fdot2(__builtin_shufflevector(a,a,4,5), __builtin_shufflevector(b,b,4,5), acc, false);
  acc = __builtin_amdgcn_fdot2(__builtin_shufflevector(a,a,6,7), __builtin_shufflevector(b,b,6,7), acc, false);
  return acc;
}
DEVI float dot4f(f16x4 a, f16x4 b, float acc) {
  acc = __builtin_amdgcn_fdot2(__builtin_shufflevector(a,a,0,1), __builtin_shufflevector(b,b,0,1), acc, false);
  acc = __builtin_amdgcn_fdot2(__builtin_shufflevector(a,a,2,3), __builtin_shufflevector(b,b,2,3), acc, false);
  return acc;
}

// DPP all-VALU wave64 reductions. REQUIRES v >= 0 (bound_ctrl 0-fill safe).
#define DPP_STEP(OP, CTRL)                                                        \
  { int t_ = __builtin_amdgcn_update_dpp(0, __builtin_bit_cast(int, v), CTRL, 0xF, 0xF, true); \
    v = OP(v, __builtin_bit_cast(float, t_)); }
DEVI float addf(float a, float b) { return a + b; }
DEVI float redmax64(float v) {
  DPP_STEP(fmaxf, 0x111) DPP_STEP(fmaxf, 0x112) DPP_STEP(fmaxf, 0x114)
  DPP_STEP(fmaxf, 0x118) DPP_STEP(fmaxf, 0x142) DPP_STEP(fmaxf, 0x143)
  return __builtin_bit_cast(float, __builtin_amdgcn_readlane(__builtin_bit_cast(int, v), 63));
}
DEVI float redsum64(float v) {
  DPP_STEP(addf, 0x111) DPP_STEP(addf, 0x112) DPP_STEP(addf, 0x114)
  DPP_STEP(addf, 0x118) DPP_STEP(addf, 0x142) DPP_STEP(addf, 0x143)
  return __builtin_bit_cast(float, __builtin_amdgcn_readlane(__builtin_bit_cast(int, v), 63));
}

// LDS-only barrier; memory clobber also pins the per-step weight loads in-loop.
DEVI void lbar() { asm volatile("s_waitcnt lgkmcnt(0)\ns_barrier" ::: "memory"); }

// ================= setup: tables + fragment-packed weights =================
__global__ void dt_setup(const float* __restrict__ embT, const float* __restrict__ Wce,
                         const float* __restrict__ bce,
                         const float* __restrict__ Wq, const float* __restrict__ bq,
                         const float* __restrict__ Wk, const float* __restrict__ bk,
                         const float* __restrict__ Wff, const float* __restrict__ Wre,
                         const float* __restrict__ Wbc, char* __restrict__ ws) {
  __shared__ float ap[LL*60];
  const int tid = threadIdx.x, bid = blockIdx.x;
  if (bid <= 1) {
    for (int i = tid; i < LL*30; i += 256) {
      int p = i / 30, k = i % 30;
      float freq = powf(10000.f, 2.0f*(float)k/60.0f);
      float ang = (float)p / freq;
      ap[p*60 + k]      = sinf(ang);
      ap[p*60 + 30 + k] = cosf(ang);
    }
    __syncthreads();
    const float* W = (bid == 0) ? Wq : Wk;
    const float* bi = (bid == 0) ? bq : bk;
    float* dst = (float*)(ws + (bid == 0 ? WS_PQ : WS_PK));
    for (int i = tid; i < LL*112; i += 256) {
      int r = i / 112, j = i % 112;
      float a = 0.f;
      if (j < ATT) {
        a = bi[j];
        for (int f = 0; f < 60; ++f) a += ap[r*60 + f]*W[f*ATT + j];
      }
      dst[i] = a;
    }
  } else if (bid == 2) {
    fp16* tbl = (fp16*)(ws + WS_TBL);
    for (int i = tid; i < ALPHA*CTX; i += 256) {
      int r = i / CTX, o = i % CTX;
      float a = bce[o];
      for (int e = 0; e < 40; ++e) a += embT[r*40 + e]*Wce[e*CTX + o];
      tbl[TBL_CE + i] = (fp16)a;
    }
    for (int i = tid; i < ALPHA*40; i += 256) tbl[TBL_EM + i] = (fp16)embT[i];
  } else if (bid == 3) {
    fp16* tbl = (fp16*)(ws + WS_TBL);
    for (int i = tid; i < 112*72; i += 256) {
      int a = i / 72, c = i % 72;
      float v = 0.f;
      if (a < ATT) {
        if (c < 20)      v = Wk[(60 + c)*ATT + a];
        else if (c < 60) v = Wk[(80 + (c-20))*ATT + a];
      }
      tbl[TBL_WK + i] = (fp16)v;
    }
  } else {
    fp16* pw = (fp16*)(ws + WS_FRAG);
    for (int gi = (bid-4)*256 + tid; gi < FRAG_TOT; gi += 28*256) {
      int t = gi, img, base, KT;
      if      (t < FF_OFF)  { img = 0; base = t - FQ_OFF;  KT = 5; }
      else if (t < FR_OFF)  { img = 1; base = t - FF_OFF;  KT = 7; }
      else if (t < FB_OFF)  { img = 2; base = t - FR_OFF;  KT = 4; }
      else if (t < FTQ_OFF) { img = 3; base = t - FB_OFF;  KT = 1; }
      else if (t < FTF_OFF) { img = 4; base = t - FTQ_OFF; KT = 2; }
      else                  { img = 5; base = t - FTF_OFF; KT = 2; }
      int j = base & 7, lane = (base >> 3) & 63, frag = base >> 9;
      int nt = frag / KT, kt = frag % KT;
      int k = kt*32 + ((lane >> 4) << 3) + j;
      int n = nt*16 + (lane & 15);
      float v = 0.f;
      if (img == 0) {
        if (n < ATT) {
          if (k < 128)      v = Wq[(80 + k)*ATT + n];
          else if (k < 148) v = Wq[(60 + (k - 128))*ATT + n];
        }
      } else if (img == 1) {
        if (k < 128)      v = Wff[(228 + k)*ALPHA + n];
        else if (k < 188) v = Wff[(k - 128)*ALPHA + n];
        else if (k < 208) v = Wff[(208 + (k - 188))*ALPHA + n];
      } else if (img == 2) {
        if (k < 128 && n < CTX) v = Wre[k*CTX + n];
      } else if (img == 3) {
        if (k < CTX && n < CTX) v = Wbc[k*CTX + n];
      } else if (img == 4) {
        if (n < ATT && k < 64)  v = Wq[(208 + k)*ATT + n];
      } else {
        if (k < 64)             v = Wff[(356 + k)*ALPHA + n];
      }
      pw[gi] = (fp16)v;
    }
  }
}

// ================= encode: ctxt + K + V, one batch elem per block =================
__global__ void dt_encode(const int* __restrict__ lemma,
    const float* __restrict__ Wb4, const float* __restrict__ bb4,
    const float* __restrict__ Waft, const float* __restrict__ baft,
    const float* __restrict__ Wall, const float* __restrict__ ball,
    char* __restrict__ ws) {
  __shared__ fp16 wkl[112*72];
  __shared__ float wb4[800], wa[400], wl[800];
  __shared__ float cel[LL*CTX], b4l[LL*CTX], afl[LL*CTX];
  __shared__ fp16 xin[LL*72];
  __shared__ float bi4[CTX], biA[CTX], biL[CTX];
  __shared__ int lem[52];
  const int b = blockIdx.x, tid = threadIdx.x;
  const fp16* ceg = (const fp16*)(ws + WS_TBL) + TBL_CE;
  const fp16* emg = (const fp16*)(ws + WS_TBL) + TBL_EM;

  { const uint4* s = (const uint4*)((const fp16*)(ws + WS_TBL) + TBL_WK);
    uint4* d = (uint4*)wkl;
    for (int i = tid; i < 112*72*2/16; i += 256) d[i] = s[i]; }
  { const float4* s = (const float4*)Wb4; float4* d = (float4*)wb4;
    for (int i = tid; i < 200; i += 256) d[i] = s[i]; }
  { const float4* s = (const float4*)Waft; float4* d = (float4*)wa;
    for (int i = tid; i < 100; i += 256) d[i] = s[i]; }
  { const float4* s = (const float4*)Wall; float4* d = (float4*)wl;
    for (int i = tid; i < 200; i += 256) d[i] = s[i]; }
  if (tid < CTX) { bi4[tid] = bb4[tid]; biA[tid] = baft[tid]; biL[tid] = ball[tid]; }
  if (tid < LL) lem[tid] = lemma[tid*BB + b];
  __syncthreads();

  for (int i = tid; i < LL*CTX; i += 256)
    cel[i] = (float)ceg[lem[i/CTX]*CTX + (i % CTX)];
  __syncthreads();

  for (int i = tid; i < LL*CTX; i += 256) {
    int l = i / CTX, o = i % CTX;
    float a = bi4[o];
    for (int c = 0; c < CTX; ++c) {
      float c2 = (l >= 2) ? cel[(l-2)*CTX + c] : 0.f;
      float c1 = (l >= 1) ? cel[(l-1)*CTX + c] : 0.f;
      a += c2*wb4[c*CTX + o] + c1*wb4[(CTX+c)*CTX + o];
    }
    b4l[i] = sigm(a);
    float af = biA[o];
    if (l < LL-1)
      for (int c = 0; c < CTX; ++c) af += cel[(l+1)*CTX + c]*wa[c*CTX + o];
    afl[i] = sigm(af);
  }
  __syncthreads();

  for (int i = tid; i < LL*CTX; i += 256) {
    int l = i / CTX, o = i % CTX;
    float a = biL[o];
    for (int c = 0; c < CTX; ++c)
      a += b4l[l*CTX + c]*wl[c*CTX + o] + afl[l*CTX + c]*wl[(CTX+c)*CTX + o];
    xin[l*72 + o] = (fp16)sigm(a);
  }
  for (int i = tid; i < LL*40; i += 256) {
    int l = i / 40, d = i % 40;
    xin[l*72 + 20 + d] = emg[lem[l]*40 + d];
  }
  for (int i = tid; i < LL*12; i += 256) {
    int l = i / 12, c = i % 12;
    xin[l*72 + 60 + c] = (fp16)0.f;
  }
  __syncthreads();

  const float* pkg = (const float*)(ws + WS_PK);
  fp16* Kw = (fp16*)(ws + WS_K) + (size_t)b*5200;
  for (int i = tid; i < 5200; i += 256) {
    int l = i / 104, a = i % 104;
    fp16 v = (fp16)0.f;
    if (a < ATT) {
      float acc = pkg[l*112 + a];
      const fp16* x = xin + l*72;
      const fp16* wv = wkl + a*72;
      #pragma unroll
      for (int k = 0; k < 9; ++k)
        acc = dot8f(*(const f16x8*)(x + 8*k), *(const f16x8*)(wv + 8*k), acc);
      v = (fp16)sigm(acc);
    }
    Kw[i] = v;
  }
  fp16* Vw = (fp16*)(ws + WS_V) + (size_t)b*3120;
  for (int i = tid; i < 3120; i += 256) {
    int d = i / 52, l = i % 52;
    Vw[i] = (l < LL) ? xin[l*72 + d] : (fp16)0.f;
  }
}

// ====== decoder: 16 waves/16 elems, single fill (256 blocks) ======
// Register plan for the 64-arch budget (1024-thread default):
//   - K lives as 12 MFMA B-fragments (48 regs, MFMA-only -> AGPR file)
//   - role weights (Wq/Wff/Wre/Wbc) streamed from global EVERY step (L2/L3-hot,
//     transient VGPRs; lbar()'s memory clobber blocks LICM re-hoisting)
//   - V + all state in LDS; scores via MFMA, PV + softmaxes on VALU
__global__ __launch_bounds__(1024)
void dt_decoder(const char* __restrict__ ws, const float* __restrict__ tags,
                const float* __restrict__ b_re, const float* __restrict__ b_bc,
                const float* __restrict__ bff, float* __restrict__ out) {
  extern __shared__ char sm[];
  fp16* xq   = (fp16*)(sm + OFF_XQ);
  fp16* xf   = (fp16*)(sm + OFF_XF);
  fp16* rp   = (fp16*)(sm + OFF_RP);
  fp16* qb   = (fp16*)(sm + OFF_QB);
  fp16* sc   = (fp16*)(sm + OFF_SC);
  fp16* atb  = (fp16*)(sm + OFF_AT);
  fp16* tagq = (fp16*)(sm + OFF_TQ);
  fp16* tagf = (fp16*)(sm + OFF_TF);
  fp16* ctxs = (fp16*)(sm + OFF_CX);
  float* bbv = (float*)(sm + OFF_BB);
  float* scw = (float*)(sm + OFF_SCW);
  fp16* Vl   = (fp16*)(sm + OFF_V);
  fp16* tagsl = (fp16*)(sm + OFF_QB);   // prologue overlay on qb (2304 <= 3328)

  const int tid = threadIdx.x, lane = tid & 63, w = tid >> 6;
  const int quad = lane >> 4, col = lane & 15;
  const int koff = quad * 8, r0 = quad * 4;
  const int b0 = blockIdx.x * EPB;
  const int b = b0 + w;                 // this wave's batch elem

  // ---- prologue: zero state region [xq..atb] ----
  { uint* z = (uint*)sm;
    for (int j = tid; j < OFF_TQ/4; j += 1024) z[j] = 0; }
  // V stage: 16 elems, coalesced (99840 B)
  { const uint4* s = (const uint4*)(ws + WS_V + (size_t)b0*6240);
    uint4* d = (uint4*)Vl;
    for (int j = tid; j < EPB*390; j += 1024) d[j] = s[j]; }
  if (tid < CTX) { bbv[tid] = b_re[tid]; bbv[20 + tid] = b_bc[tid]; }
  __syncthreads();   // zeros (incl. tagsl overlay region) visible

  // tags into tagsl rows 0..15 (exactly 1024 values)
  { int e = tid >> 6, c = tid & 63;
    tagsl[e*72 + c] = (fp16)tags[(size_t)(b0 + e)*64 + c]; }
  if (tid < EPB) { xq[tid*XQS + 1] = (fp16)1.f; xf[tid*XFS + 1] = (fp16)1.f; }
  if (tid < EPB*CTX) {
    int r = tid / CTX, o = tid % CTX;
    float c1 = sigm(b_bc[o]);
    xq[r*XQS + 128 + o] = (fp16)c1;
    xf[r*XFS + 188 + o] = (fp16)c1;
  }
  for (int j = tid; j < EPB*128; j += 1024) {
    int e = j >> 7, o = j & 127;
    out[(size_t)(b0 + e)*ALPHA + o] = (o == 1) ? 1.f : 0.f;
  }
  __syncthreads();

  // ---- tag projections via MFMA (transient frag regs, weights from global) ----
  const fp16* fw = (const fp16*)(ws + WS_FRAG);
  {
    f16x8 a0 = *(const f16x8*)(tagsl + col*72 + koff);
    f16x8 a1 = *(const f16x8*)(tagsl + col*72 + 32 + koff);
    if (w < 7) {
      f16x8 t0 = *(const f16x8*)(fw + FTQ_OFF + (((w*2 + 0) << 6) + lane)*8);
      f16x8 t1 = *(const f16x8*)(fw + FTQ_OFF + (((w*2 + 1) << 6) + lane)*8);
      f32x4 c = {0.f,0.f,0.f,0.f};
      c = mfma16(a0, t0, c); c = mfma16(a1, t1, c);
      const int colg = w*16 + col;
      if (colg < 104) {
        #pragma unroll
        for (int r = 0; r < 4; ++r) tagq[(r0 + r)*TQS + colg] = (fp16)c[r];
      }
    } else if (w >= 8) {
      const float bffr = bff[(w-8)*16 + col];
      f16x8 u0 = *(const f16x8*)(fw + FTF_OFF + ((((w-8)*2 + 0) << 6) + lane)*8);
      f16x8 u1 = *(const f16x8*)(fw + FTF_OFF + ((((w-8)*2 + 1) << 6) + lane)*8);
      f32x4 d = {0.f,0.f,0.f,0.f};
      d = mfma16(a0, u0, d); d = mfma16(a1, u1, d);
      const int colg = (w-8)*16 + col;
      #pragma unroll
      for (int r = 0; r < 4; ++r) tagf[(r0 + r)*128 + colg] = (fp16)(d[r] + bffr);
    }
  }

  // ---- persistent: K as 12 MFMA B-fragments (AGPR-friendly) + f16x4 tail ----
  // B-frag layout (16x16x32): lane holds B[k=c*32+quad*8+j][n=t*16+col];
  // B[k][n] = K[pos=n][dim=k]  (scores D = q . K^T).
  f16x8 KF[12];
  f16x4 ktail;
  { const fp16* kg = (const fp16*)(ws + WS_K) + (size_t)b*5200;
    #pragma unroll
    for (int c = 0; c < 3; ++c) {
      #pragma unroll
      for (int t = 0; t < 4; ++t) {
        int pos = t*16 + col; if (pos >= LL) pos = LL-1;   // clamped rows masked later
        KF[c*4 + t] = *(const f16x8*)(kg + pos*104 + c*32 + koff);
      }
    }
    int pl = (lane < LL) ? lane : LL-1;
    ktail = *(const f16x4*)(kg + pl*104 + 96);             // dims 96..99, row=lane
  }

  const float* posqg = (const float*)(ws + WS_PQ);
  const fp16* xq_a = xq + col*XQS + koff;
  const fp16* xf_a = xf + col*XFS + koff;
  const fp16* rp_a = rp + col*40 + koff;

  __syncthreads();

  float pA = 0.f, pB = 0.f;   // previous step's probs (deferred out-store)

  // ==================== recurrence ====================
  for (int i = 1; i < LL; ++i) {
    // ---- Phase A: deferred store + q-GEMM (w<7) / re+bc (w==7); weights streamed ----
    if (i > 1) {
      size_t ob = ((size_t)(i-1)*BB + b)*ALPHA;
      out[ob + lane] = pA; out[ob + 64 + lane] = pB;
    }
    if (w < 7) {
      const int colg = w*16 + col;
      float pos = posqg[i*112 + colg];
      f16x8 q0 = *(const f16x8*)(fw + FQ_OFF + (((w*5 + 0) << 6) + lane)*8);
      f16x8 q1 = *(const f16x8*)(fw + FQ_OFF + (((w*5 + 1) << 6) + lane)*8);
      f16x8 q2 = *(const f16x8*)(fw + FQ_OFF + (((w*5 + 2) << 6) + lane)*8);
      f16x8 q3 = *(const f16x8*)(fw + FQ_OFF + (((w*5 + 3) << 6) + lane)*8);
      f16x8 q4 = *(const f16x8*)(fw + FQ_OFF + (((w*5 + 4) << 6) + lane)*8);
      f32x4 c0 = {0.f,0.f,0.f,0.f}, c1 = {0.f,0.f,0.f,0.f};
      c0 = mfma16(*(const f16x8*)(xq_a + 0*32), q0, c0);
      c1 = mfma16(*(const f16x8*)(xq_a + 1*32), q1, c1);
      c0 = mfma16(*(const f16x8*)(xq_a + 2*32), q2, c0);
      c1 = mfma16(*(const f16x8*)(xq_a + 3*32), q3, c1);
      c0 = mfma16(*(const f16x8*)(xq_a + 4*32), q4, c0);
      if (colg < 104) {
        #pragma unroll
        for (int r = 0; r < 4; ++r)
          qb[(r0 + r)*QBS + colg] =
            (fp16)sigm(c0[r] + c1[r] + pos + (float)tagq[(r0 + r)*TQS + colg]);
      }
    } else if (w == 7) {
      // r(i-1) = sigm(probs(i-1) @ Wre + bre)
      f32x4 c0 = {0.f,0.f,0.f,0.f}, c1 = {0.f,0.f,0.f,0.f};
      #pragma unroll
      for (int kt = 0; kt < 4; ++kt) {
        f16x8 w0 = *(const f16x8*)(fw + FR_OFF + (((0*4 + kt) << 6) + lane)*8);
        f16x8 w1 = *(const f16x8*)(fw + FR_OFF + (((1*4 + kt) << 6) + lane)*8);
        f16x8 a = *(const f16x8*)(xq_a + kt*32);
        c0 = mfma16(a, w0, c0);
        c1 = mfma16(a, w1, c1);
      }
      const int cA = col, cB = 16 + col;
      #pragma unroll
      for (int r = 0; r < 4; ++r) {
        rp[(r0 + r)*40 + cA] = (fp16)sigm(c0[r] + bbv[cA]);
        if (cB < CTX) rp[(r0 + r)*40 + cB] = (fp16)sigm(c1[r] + bbv[cB]);
      }
      // ctx(i+1) = sigm(r(i-1) @ Wbc + bbc) -> staged (copied in phase D)
      f16x8 wb0 = *(const f16x8*)(fw + FB_OFF + ((0 << 6) + lane)*8);
      f16x8 wb1 = *(const f16x8*)(fw + FB_OFF + ((1 << 6) + lane)*8);
      f16x8 ar = *(const f16x8*)rp_a;
      f32x4 d0 = mfma16(ar, wb0, (f32x4){0.f,0.f,0.f,0.f});
      f32x4 d1 = mfma16(ar, wb1, (f32x4){0.f,0.f,0.f,0.f});
      #pragma unroll
      for (int r = 0; r < 4; ++r) {
        ctxs[(r0 + r)*20 + cA] = (fp16)sigm(d0[r] + bbv[20 + cA]);
        if (cB < CTX) ctxs[(r0 + r)*20 + cB] = (fp16)sigm(d1[r] + bbv[20 + cB]);
      }
    }
    lbar();

    // ---- Phase B (all waves, own elem): MFMA scores, softmax-50, VALU PV ----
    {
      // scores D[e][pos]: A = all elems' q (LDS), B = this elem's K frags (regs)
      f32x4 s0 = {0.f,0.f,0.f,0.f}, s1 = {0.f,0.f,0.f,0.f};
      f32x4 s2 = {0.f,0.f,0.f,0.f}, s3 = {0.f,0.f,0.f,0.f};
      #pragma unroll
      for (int c = 0; c < 3; ++c) {
        f16x8 a = *(const f16x8*)(qb + col*QBS + c*32 + koff);
        s0 = mfma16(a, KF[c*4 + 0], s0);
        s1 = mfma16(a, KF[c*4 + 1], s1);
        s2 = mfma16(a, KF[c*4 + 2], s2);
        s3 = mfma16(a, KF[c*4 + 3], s3);
      }
      // extract row w (held by lane group w>>2, reg w&3) into score scratch
      if (quad == (w >> 2)) {
        const int sel = w & 3;
        float* sw = scw + w*64;
        sw[ 0 + col] = sel==0 ? s0[0] : sel==1 ? s0[1] : sel==2 ? s0[2] : s0[3];
        sw[16 + col] = sel==0 ? s1[0] : sel==1 ? s1[1] : sel==2 ? s1[2] : s1[3];
        sw[32 + col] = sel==0 ? s2[0] : sel==1 ? s2[1] : sel==2 ? s2[2] : s2[3];
        sw[48 + col] = sel==0 ? s3[0] : sel==1 ? s3[1] : sel==2 ? s3[2] : s3[3];
      }
      // tail dims 96..99 on VALU (per-position lane)
      f16x4 qt = *(const f16x4*)(qb + w*QBS + 96);
      float s = scw[w*64 + lane] + dot4f(qt, ktail, 0.f);
      s = (lane < LL) ? s : 0.f;                    // scores >= 0
      float m  = redmax64(s);
      float e  = (lane < LL) ? __expf(s - m) : 0.f;
      float su = redsum64(e);
      if (lane < LL) atb[w*ATS + lane] = (fp16)(e * rcpf(su));
      // PV: lane d reads V row d from LDS
      const fp16* ar = atb + w*ATS;
      const fp16* vr = Vl + (w*60 + ((lane < 60) ? lane : 59))*52;
      float v0 = 0.f, v1 = 0.f;
      #pragma unroll
      for (int k = 0; k < 12; k += 2) {
        v0 = dot4f(*(const f16x4*)(ar + 4*k),     *(const f16x4*)(vr + 4*k),     v0);
        v1 = dot4f(*(const f16x4*)(ar + 4*(k+1)), *(const f16x4*)(vr + 4*(k+1)), v1);
      }
      v0 = dot4f(*(const f16x4*)(ar + 48), *(const f16x4*)(vr + 48), v0);
      if (lane < 60) xf[w*XFS + 128 + lane] = (fp16)(v0 + v1);
    }
    lbar();

    // ---- Phase C (w>=8): ff-GEMM, weights streamed ----
    if (w >= 8) {
      const int colg = (w-8)*16 + col;
      f16x8 f0 = *(const f16x8*)(fw + FF_OFF + ((((w-8)*7 + 0) << 6) + lane)*8);
      f16x8 f1 = *(const f16x8*)(fw + FF_OFF + ((((w-8)*7 + 1) << 6) + lane)*8);
      f16x8 f2 = *(const f16x8*)(fw + FF_OFF + ((((w-8)*7 + 2) << 6) + lane)*8);
      f16x8 f3 = *(const f16x8*)(fw + FF_OFF + ((((w-8)*7 + 3) << 6) + lane)*8);
      f16x8 f4 = *(const f16x8*)(fw + FF_OFF + ((((w-8)*7 + 4) << 6) + lane)*8);
      f16x8 f5 = *(const f16x8*)(fw + FF_OFF + ((((w-8)*7 + 5) << 6) + lane)*8);
      f16x8 f6 = *(const f16x8*)(fw + FF_OFF + ((((w-8)*7 + 6) << 6) + lane)*8);
      f32x4 c0 = {0.f,0.f,0.f,0.f}, c1 = {0.f,0.f,0.f,0.f};
      c0 = mfma16(*(const f16x8*)(xf_a + 0*32), f0, c0);
      c1 = mfma16(*(const f16x8*)(xf_a + 1*32), f1, c1);
      c0 = mfma16(*(const f16x8*)(xf_a + 2*32), f2, c0);
      c1 = mfma16(*(const f16x8*)(xf_a + 3*32), f3, c1);
      c0 = mfma16(*(const f16x8*)(xf_a + 4*32), f4, c0);
      c1 = mfma16(*(const f16x8*)(xf_a + 5*32), f5, c1);
      c0 = mfma16(*(const f16x8*)(xf_a + 6*32), f6, c0);
      #pragma unroll
      for (int r = 0; r < 4; ++r)
        sc[(r0 + r)*SCS + colg] =
          (fp16)sigm(c0[r] + c1[r] + (float)tagf[(r0 + r)*128 + colg]);
    }
    lbar();

    // ---- Phase D (all waves, own elem): softmax-128; wave 7 also ctx copy ----
    {
      float v0 = (float)sc[w*SCS + lane], v1 = (float)sc[w*SCS + 64 + lane];
      float m = redmax64(fmaxf(v0, v1));
      float e0 = __expf(v0 - m), e1 = __expf(v1 - m);
      float su = redsum64(e0 + e1);
      float inv = rcpf(su);
      pA = e0 * inv; pB = e1 * inv;
      xq[w*XQS + lane] = (fp16)pA; xq[w*XQS + 64 + lane] = (fp16)pB;
      xf[w*XFS + lane] = (fp16)pA; xf[w*XFS + 64 + lane] = (fp16)pB;
    }
    if (w == 7) {
      int r = lane & 15, cg = (lane >> 4) * 5;
      #pragma unroll
      for (int j = 0; j < 5; ++j) {
        fp16 t = ctxs[r*20 + cg + j];
        xq[r*XQS + 128 + cg + j] = t;
        xf[r*XFS + 188 + cg + j] = t;
      }
    }
    lbar();
  }
  { size_t ob = ((size_t)(LL-1)*BB + b)*ALPHA;
    out[ob + lane] = pA; out[ob + 64 + lane] = pB; }
}

extern "C" void kernel_launch(void* const* d_in, const int* in_sizes, int n_in,
                              void* d_out, int out_size, void* d_ws, size_t ws_size,
                              hipStream_t stream) {
  (void)in_sizes; (void)n_in; (void)out_size; (void)ws_size;
  const int*   lemma = (const int*)  d_in[0];
  const float* tags  = (const float*)d_in[1];
  const float* embT  = (const float*)d_in[2];
  const float* Wce   = (const float*)d_in[3];
  const float* bce   = (const float*)d_in[4];
  const float* Wb4   = (const float*)d_in[5];
  const float* bb4   = (const float*)d_in[6];
  const float* Waft  = (const float*)d_in[7];
  const float* baft  = (const float*)d_in[8];
  const float* Wall  = (const float*)d_in[9];
  const float* ball  = (const float*)d_in[10];
  const float* Wre   = (const float*)d_in[11];
  const float* bre   = (const float*)d_in[12];
  const float* Wbc   = (const float*)d_in[13];
  const float* bbc   = (const float*)d_in[14];
  const float* Wq    = (const float*)d_in[15];
  const float* bq    = (const float*)d_in[16];
  const float* Wk    = (const float*)d_in[17];
  const float* bk    = (const float*)d_in[18];
  const float* Wff   = (const float*)d_in[19];
  const float* bff   = (const float*)d_in[20];
  char* ws = (char*)d_ws;
  float* out = (float*)d_out;

  hipFuncSetAttribute((const void*)dt_decoder,
                      hipFuncAttributeMaxDynamicSharedMemorySize, SM_TOT);

  dt_setup<<<32, 256, 0, stream>>>(embT, Wce, bce, Wq, bq, Wk, bk, Wff, Wre, Wbc, ws);
  dt_encode<<<BB, 256, 0, stream>>>(lemma, Wb4, bb4, Waft, baft, Wall, ball, ws);
  dt_decoder<<<BB/EPB, 1024, SM_TOT, stream>>>(ws, tags, bre, bbc, bff, out);
}